// Round 12
// baseline (716.926 us; speedup 1.0000x reference)
//
#include <hip/hip_runtime.h>
#include <hip/hip_bf16.h>
#include <stdint.h>

#define NN 100000
#define NE 3200000
#define DIM 128
#define HID 512
#define BN_EPS 1e-5f
#define NBIN 128     // dst bins for 2-pass CSR build (fine enough for LDS cursors in fill2)
#define NPBIN 784    // nodes per bin (128*784 = 100352 >= NN); d_local < 784 fits 10 bits
#define TILE 2048    // edges per block-tile in pass 1 (8 per thread)
#define CAP 27000    // fixed bin capacity: mean 25088, sigma~158 -> 12-sigma slack

typedef short short8 __attribute__((ext_vector_type(8)));
typedef float floatx4 __attribute__((ext_vector_type(4)));

__device__ __forceinline__ float bfu2f(unsigned short u) {
    return __uint_as_float(((unsigned int)u) << 16);
}
__device__ __forceinline__ unsigned short f2bfu(float f) {
    union { __hip_bfloat16 h; unsigned short u; } cv;
    cv.h = __float2bfloat16(f);
    return cv.u;
}

// ---------------- init: bin cursors (fixed-capacity regions) + BN stat accumulators ----------------
__global__ void k_init(int* __restrict__ bincur, float* __restrict__ stats) {
    int i = blockIdx.x * 256 + threadIdx.x;
    if (i < NBIN) bincur[i] = i * CAP;
    if (i < 512) stats[i] = 0.f;   // [0..127]=sum1,[128..255]=sq1,[256..383]=sum2,[384..511]=sq2
}

// ---------------- CSR build pass 1: LDS multi-split into 128 FIXED-CAPACITY dst-bin regions ----
__global__ __launch_bounds__(256) void k_fill1(const int* __restrict__ src, const int* __restrict__ dst,
                                               int* __restrict__ bincur, unsigned int* __restrict__ recs) {
    __shared__ int lhist[NBIN], lbase[NBIN], gbase[NBIN];
    __shared__ unsigned int lrec[TILE];
    int tid = threadIdx.x;
    int tbase = blockIdx.x * TILE;
    if (tid < NBIN) lhist[tid] = 0;
    __syncthreads();
    unsigned int myrec[8];
    int mybin[8], myrank[8];
    #pragma unroll
    for (int j = 0; j < 8; ++j) {
        int e = tbase + j * 256 + tid;
        mybin[j] = -1;
        if (e < NE) {
            int d = __builtin_nontemporal_load(dst + e);
            int s = __builtin_nontemporal_load(src + e);
            int b = d / NPBIN;            // 0..127
            myrec[j] = (unsigned)s | ((unsigned)(d - b * NPBIN) << 17);
            mybin[j] = b;
            myrank[j] = atomicAdd(&lhist[b], 1);
        }
    }
    __syncthreads();
    if (tid == 0) {                        // exclusive scan of 128 bin counts
        int run = 0;
        #pragma unroll
        for (int b = 0; b < NBIN; ++b) { lbase[b] = run; run += lhist[b]; }
    }
    __syncthreads();
    if (tid < NBIN) gbase[tid] = atomicAdd(&bincur[tid], lhist[tid]);
    __syncthreads();
    #pragma unroll
    for (int j = 0; j < 8; ++j)
        if (mybin[j] >= 0) lrec[lbase[mybin[j]] + myrank[j]] = myrec[j];
    __syncthreads();
    int total = lbase[NBIN - 1] + lhist[NBIN - 1];
    for (int i = tid; i < total; i += 256) {
        int b = 0;                         // largest b with lbase[b] <= i (lbase monotone)
        #pragma unroll
        for (int st = NBIN / 2; st > 0; st >>= 1)
            if (b + st < NBIN && lbase[b + st] <= i) b += st;
        int p = gbase[b] + (i - lbase[b]);
        if (p < (b + 1) * CAP) recs[p] = lrec[i];   // capacity guard (12-sigma slack)
    }
}

// ---------------- per-bin LDS histogram -> cnt, one block per bin, NO global atomics --------
__global__ __launch_bounds__(256) void k_cnt(const unsigned int* __restrict__ recs,
                                             const int* __restrict__ bincur,
                                             int* __restrict__ cnt) {
    __shared__ int lhist[NPBIN];
    int b = blockIdx.x;
    int tid = threadIdx.x;
    for (int i = tid; i < NPBIN; i += 256) lhist[i] = 0;
    __syncthreads();
    int start = b * CAP;
    int end = bincur[b];
    if (end > start + CAP) end = start + CAP;
    if (end < start) end = start;
    for (int i = start + tid; i < end; i += 256) {
        unsigned int r = __builtin_nontemporal_load(recs + i);
        int dl = (int)(r >> 17);
        if (dl < NPBIN) atomicAdd(&lhist[dl], 1);
    }
    __syncthreads();
    for (int i = tid; i < NPBIN; i += 256) {
        int n = b * NPBIN + i;
        if (n < NN) cnt[n] = lhist[i];
    }
}

// ---------------- scan stage A: per-block (1024-wide) local exclusive scan + block sums + dinv ----
__global__ __launch_bounds__(1024) void k_scanA(const int* __restrict__ cnt, int* __restrict__ offs,
                                                int* __restrict__ bsum, float* __restrict__ dinv) {
    __shared__ int wsum[16];
    int t = threadIdx.x;          // 1024 threads = 16 waves
    int lane = t & 63, wid = t >> 6;
    int i = blockIdx.x * 1024 + t;
    int v = (i < NN) ? cnt[i] : 0;
    int incl = v;
    #pragma unroll
    for (int off = 1; off < 64; off <<= 1) {
        int y = __shfl_up(incl, off, 64);
        if (lane >= off) incl += y;
    }
    if (lane == 63) wsum[wid] = incl;
    __syncthreads();
    if (wid == 0) {
        int wv = (lane < 16) ? wsum[lane] : 0;
        int wincl = wv;
        #pragma unroll
        for (int off = 1; off < 16; off <<= 1) {
            int y = __shfl_up(wincl, off, 64);
            if (lane >= off) wincl += y;
        }
        if (lane < 16) wsum[lane] = wincl - wv;   // exclusive wave offsets
    }
    __syncthreads();
    int excl = wsum[wid] + incl - v;              // block-local exclusive
    if (i < NN) {
        offs[i] = excl;
        dinv[i] = rsqrtf((float)(v + 1));         // deg includes self-loop
    }
    if (t == 1023) bsum[blockIdx.x] = excl + v;   // block total
}

// ---------------- scan stage B: single block scans the 98 block sums ----------------
__global__ __launch_bounds__(128) void k_scanB(int* __restrict__ bsum, int* __restrict__ offs, int nblk) {
    int t = threadIdx.x;   // 128 >= nblk; two waves, use wave 0 only
    if (t < 64) {
        int v = (t < nblk) ? bsum[t] : 0;
        int v2 = (t + 64 < nblk) ? bsum[t + 64] : 0;
        int incl = v;
        #pragma unroll
        for (int off = 1; off < 64; off <<= 1) {
            int y = __shfl_up(incl, off, 64);
            if (t >= off) incl += y;
        }
        int tot0 = __shfl(incl, 63, 64);
        int incl2 = v2;
        #pragma unroll
        for (int off = 1; off < 64; off <<= 1) {
            int y = __shfl_up(incl2, off, 64);
            if (t >= off) incl2 += y;
        }
        if (t < nblk) bsum[t] = incl - v;                      // exclusive
        if (t + 64 < nblk) bsum[t + 64] = tot0 + incl2 - v2;
        if (t == 63) offs[NN] = tot0 + __shfl(incl2, 63, 64);  // grand total
    }
}

// ---------------- scan stage C: add block bases ----------------
__global__ void k_scanC(int* __restrict__ offs, const int* __restrict__ bsum) {
    int i = blockIdx.x * 256 + threadIdx.x;
    if (i < NN) offs[i] += bsum[i >> 10];
}

// ---------------- CSR build pass 2: per-bin scatter with LDS cursors, ZERO global atomics ----
__global__ __launch_bounds__(256) void k_fill2(const unsigned int* __restrict__ recs,
                                               const int* __restrict__ bincur,
                                               const int* __restrict__ offs,
                                               int* __restrict__ srcs) {
    __shared__ int loffs[NPBIN], lcur[NPBIN];
    int b = blockIdx.x;
    int tid = threadIdx.x;
    for (int i = tid; i < NPBIN; i += 256) {
        int n = b * NPBIN + i;
        loffs[i] = (n <= NN) ? offs[n] : NE;
        lcur[i] = 0;
    }
    __syncthreads();
    int start = b * CAP;
    int end = bincur[b];
    if (end > start + CAP) end = start + CAP;
    if (end < start) end = start;
    for (int i = start + tid; i < end; i += 256) {
        unsigned int r = __builtin_nontemporal_load(recs + i);
        int s = (int)(r & 0x1FFFFu);
        int dl = (int)(r >> 17);
        if (dl < NPBIN) {
            int p = loffs[dl] + atomicAdd(&lcur[dl], 1);
            if ((unsigned)p < NE) srcs[p] = s;
        }
    }
}

// ---------------- transpose W (fp32) -> bf16 wt[n][k] ----------------
__global__ void k_wt(const float* __restrict__ W, unsigned short* __restrict__ wt) {
    int i = blockIdx.x * 256 + threadIdx.x;
    if (i < DIM * DIM) {
        int k = i >> 7, n = i & 127;
        wt[n * DIM + k] = f2bfu(W[k * DIM + n]);
    }
}

// ---------------- prep FF weights: w1t[n=512][k=128], w2t[n=128][k=512] (bf16, transposed) -------
__global__ void k_prep(const float* __restrict__ w1, const float* __restrict__ w2,
                       unsigned short* __restrict__ w1t, unsigned short* __restrict__ w2t) {
    int i = blockIdx.x * 256 + threadIdx.x;
    if (i < HID * DIM) {
        int n1 = i >> 7, k1 = i & 127;           // w1t[n1*128+k1] = w1[k1*512+n1]
        w1t[i] = f2bfu(w1[k1 * HID + n1]);
        int n2 = i & 127, k2 = i >> 7;           // w2t[n2*512+k2] = w2[k2*DIM+n2]
        w2t[n2 * HID + k2] = f2bfu(w2[k2 * DIM + n2]);
    }
}

// ---------------- xw' = dinv .* (bf16(x) @ bf16(W)) via MFMA; dinv folded ----------------
__global__ __launch_bounds__(256) void k_gemm1(const float* __restrict__ x,
                                               const unsigned short* __restrict__ wt,
                                               const float* __restrict__ dinv,
                                               unsigned short* __restrict__ xw) {
    int wave = threadIdx.x >> 6;
    int lane = threadIdx.x & 63;
    int row0 = blockIdx.x * 64 + wave * 16;
    int arow = row0 + (lane & 15);
    if (arow >= NN) arow = NN - 1;        // clamp; stores are guarded
    int kbase = (lane >> 4) * 8;
    const float* xr = x + (size_t)arow * DIM;
    short8 afrag[4];
    #pragma unroll
    for (int kt = 0; kt < 4; ++kt) {
        float4 f0 = *(const float4*)(xr + kt * 32 + kbase);
        float4 f1 = *(const float4*)(xr + kt * 32 + kbase + 4);
        short8 a;
        a[0] = (short)f2bfu(f0.x); a[1] = (short)f2bfu(f0.y);
        a[2] = (short)f2bfu(f0.z); a[3] = (short)f2bfu(f0.w);
        a[4] = (short)f2bfu(f1.x); a[5] = (short)f2bfu(f1.y);
        a[6] = (short)f2bfu(f1.z); a[7] = (short)f2bfu(f1.w);
        afrag[kt] = a;                     // A[m=lane&15][k=quad*8+j]
    }
    int crow = row0 + (lane >> 4) * 4;
    float dv[4];
    #pragma unroll
    for (int i = 0; i < 4; ++i) {
        int r = crow + i;
        dv[i] = dinv[r < NN ? r : NN - 1];
    }
    #pragma unroll
    for (int ct = 0; ct < 8; ++ct) {
        int ncol = ct * 16 + (lane & 15);
        const short* wr = (const short*)wt + (size_t)ncol * DIM;
        floatx4 acc = {0.f, 0.f, 0.f, 0.f};
        #pragma unroll
        for (int kt = 0; kt < 4; ++kt) {
            short8 bfrag = *(const short8*)(wr + kt * 32 + kbase); // B[k=quad*8+j][n=lane&15]
            acc = __builtin_amdgcn_mfma_f32_16x16x32_bf16(afrag[kt], bfrag, acc, 0, 0, 0);
        }
        #pragma unroll
        for (int i = 0; i < 4; ++i) {
            int r = crow + i;                  // C: row=(lane>>4)*4+reg, col=lane&15
            if (r < NN) xw[(size_t)r * DIM + ct * 16 + (lane & 15)] = f2bfu(acc[i] * dv[i]);
        }
    }
}

// ---------------- aggregate v4: register-blocked indices + QUAD edge pairing ----------------
__global__ __launch_bounds__(256) void k_aggregate(const unsigned int* __restrict__ xw2,
                                                   const int* __restrict__ offs,
                                                   const int* __restrict__ srcs,
                                                   const float* __restrict__ dinv,
                                                   const float* __restrict__ x,
                                                   const float* __restrict__ bias,
                                                   unsigned int* __restrict__ u) {
    int node = blockIdx.x * 4 + (threadIdx.x >> 6);
    if (node >= NN) return;
    int lane = threadIdx.x & 63;
    int qt = lane >> 4;              // edge slot within quad (0..3)
    int ql = lane & 15;              // handles cols 8*ql .. 8*ql+7
    int beg = offs[node], end = offs[node + 1];
    beg = max(0, min(beg, NE));
    end = max(beg, min(end, NE));
    int ne = end - beg;
    float a[8];
    #pragma unroll
    for (int j = 0; j < 8; ++j) a[j] = 0.f;
    const uint4* xw16 = (const uint4*)xw2;       // row = 16 uint4 (256B)
    for (int base = 0; base < ne; base += 64) {
        int rem = ne - base;
        if (rem > 64) rem = 64;
        int sidx = (lane < rem) ? srcs[beg + base + lane] : 0;
        #pragma unroll 4
        for (int i = 0; i < rem; i += 4) {
            int want = i + qt;
            int s = __builtin_amdgcn_ds_bpermute(want << 2, sidx);
            if (want < rem) {
                if ((unsigned)s >= NN) s = 0;
                uint4 pk = xw16[(size_t)s * 16 + ql];
                a[0] += __uint_as_float(pk.x << 16);
                a[1] += __uint_as_float(pk.x & 0xffff0000u);
                a[2] += __uint_as_float(pk.y << 16);
                a[3] += __uint_as_float(pk.y & 0xffff0000u);
                a[4] += __uint_as_float(pk.z << 16);
                a[5] += __uint_as_float(pk.z & 0xffff0000u);
                a[6] += __uint_as_float(pk.w << 16);
                a[7] += __uint_as_float(pk.w & 0xffff0000u);
            }
        }
    }
    // combine the 4 quad partial sums (all lanes end with the full sum)
    #pragma unroll
    for (int j = 0; j < 8; ++j) {
        a[j] += __shfl_xor(a[j], 16, 64);
        a[j] += __shfl_xor(a[j], 32, 64);
    }
    if (qt == 0) {                   // lanes 0..15 write the 256B row
        uint4 ps = xw16[(size_t)node * 16 + ql];
        float di = dinv[node];
        const float* xr = x + (size_t)node * DIM + ql * 8;
        float4 xv0 = *(const float4*)xr;
        float4 xv1 = *(const float4*)(xr + 4);
        float4 bv0 = *(const float4*)(bias + ql * 8);
        float4 bv1 = *(const float4*)(bias + ql * 8 + 4);
        float o0 = xv0.x + bv0.x + di * (a[0] + __uint_as_float(ps.x << 16));
        float o1 = xv0.y + bv0.y + di * (a[1] + __uint_as_float(ps.x & 0xffff0000u));
        float o2 = xv0.z + bv0.z + di * (a[2] + __uint_as_float(ps.y << 16));
        float o3 = xv0.w + bv0.w + di * (a[3] + __uint_as_float(ps.y & 0xffff0000u));
        float o4 = xv1.x + bv1.x + di * (a[4] + __uint_as_float(ps.z << 16));
        float o5 = xv1.y + bv1.y + di * (a[5] + __uint_as_float(ps.z & 0xffff0000u));
        float o6 = xv1.z + bv1.z + di * (a[6] + __uint_as_float(ps.w << 16));
        float o7 = xv1.w + bv1.w + di * (a[7] + __uint_as_float(ps.w & 0xffff0000u));
        uint4 pk;
        pk.x = ((unsigned int)f2bfu(o1) << 16) | (unsigned int)f2bfu(o0);
        pk.y = ((unsigned int)f2bfu(o3) << 16) | (unsigned int)f2bfu(o2);
        pk.z = ((unsigned int)f2bfu(o5) << 16) | (unsigned int)f2bfu(o4);
        pk.w = ((unsigned int)f2bfu(o7) << 16) | (unsigned int)f2bfu(o6);
        ((uint4*)u)[(size_t)node * 16 + ql] = pk;
    }
}

// ---------------- BN1 stats: per-column sum & sumsq of u (bf16) ----------------
__global__ void k_stats(const unsigned int* __restrict__ u2, float* __restrict__ stats) {
    int t = threadIdx.x;            // 256
    int c = t & 63, g = t >> 6;     // uint index c -> bf16 cols 2c, 2c+1
    float s0 = 0.f, q0 = 0.f, s1 = 0.f, q1 = 0.f;
    for (int r = blockIdx.x * 4 + g; r < NN; r += gridDim.x * 4) {
        unsigned int pv = u2[(size_t)r * 64 + c];
        float x0 = __uint_as_float(pv << 16);
        float x1 = __uint_as_float(pv & 0xffff0000u);
        s0 += x0; q0 += x0 * x0; s1 += x1; q1 += x1 * x1;
    }
    __shared__ float A[256], B[256], C[256], D2[256];
    A[t] = s0; B[t] = q0; C[t] = s1; D2[t] = q1;
    __syncthreads();
    if (t < 64) {
        float rs0 = A[t] + A[t + 64] + A[t + 128] + A[t + 192];
        float rq0 = B[t] + B[t + 64] + B[t + 128] + B[t + 192];
        float rs1 = C[t] + C[t + 64] + C[t + 128] + C[t + 192];
        float rq1 = D2[t] + D2[t + 64] + D2[t + 128] + D2[t + 192];
        atomicAdd(&stats[2 * c],           rs0);
        atomicAdd(&stats[2 * c + 1],       rs1);
        atomicAdd(&stats[DIM + 2 * c],     rq0);
        atomicAdd(&stats[DIM + 2 * c + 1], rq1);
    }
}

// ---------------- BN2 stats: per-column sum & sumsq of v (fp32) ----------------
__global__ void k_stats2(const float2* __restrict__ v2, float* __restrict__ stats) {
    int t = threadIdx.x;            // 256
    int c = t & 63, g = t >> 6;     // float2 index c -> cols 2c, 2c+1
    float s0 = 0.f, q0 = 0.f, s1 = 0.f, q1 = 0.f;
    for (int r = blockIdx.x * 4 + g; r < NN; r += gridDim.x * 4) {
        float2 pv = v2[(size_t)r * 64 + c];
        s0 += pv.x; q0 += pv.x * pv.x; s1 += pv.y; q1 += pv.y * pv.y;
    }
    __shared__ float A[256], B[256], C[256], D2[256];
    A[t] = s0; B[t] = q0; C[t] = s1; D2[t] = q1;
    __syncthreads();
    if (t < 64) {
        float rs0 = A[t] + A[t + 64] + A[t + 128] + A[t + 192];
        float rq0 = B[t] + B[t + 64] + B[t + 128] + B[t + 192];
        float rs1 = C[t] + C[t + 64] + C[t + 128] + C[t + 192];
        float rq1 = D2[t] + D2[t + 64] + D2[t + 128] + D2[t + 192];
        atomicAdd(&stats[2 * c],           rs0);
        atomicAdd(&stats[2 * c + 1],       rs1);
        atomicAdd(&stats[DIM + 2 * c],     rq0);
        atomicAdd(&stats[DIM + 2 * c + 1], rq1);
    }
}

// ---------------- fused FF v4: register-prefetch pipeline for weight staging ----------------
// r11 counters: MfmaUtil 8%, HBM 7%, occupancy 17% -> latency-bound on the serial
// {barrier, stage 32KB global->LDS, barrier, compute} chunk loop. Fix (T14): prologue loads
// chunk 0 into regs; per chunk: write regs->LDS, barrier, ISSUE chunk c+1 loads, compute.
// Next chunk's ~600cy global latency hides under current chunk's MFMAs. +32 VGPR, LDS same.
__global__ __launch_bounds__(256) void k_ffx(const unsigned int* __restrict__ u2,
                                             const float* __restrict__ stats1,
                                             const float* __restrict__ gamma,
                                             const float* __restrict__ beta,
                                             const unsigned short* __restrict__ w1t,
                                             const float* __restrict__ b1,
                                             const unsigned short* __restrict__ w2t,
                                             const float* __restrict__ b2,
                                             float* __restrict__ v) {
    __shared__ __align__(16) float sscale[DIM], sshift[DIM];
    __shared__ __align__(16) unsigned int sw1[64 * 64];       // 16KB: w1 chunk [64 hid][128 k bf16]
    __shared__ __align__(16) unsigned int sw2[128 * 32];      // 16KB: w2 chunk [128 out][64 k bf16]
    __shared__ __align__(16) unsigned int hbufs[4][16 * 32];  // 8KB: per-wave h strip [16 node][64 hid]
    int tid = threadIdx.x;
    if (tid < DIM) {
        float mu  = stats1[tid] * (1.0f / NN);
        float var = stats1[DIM + tid] * (1.0f / NN) - mu * mu;
        float sc = rsqrtf(var + BN_EPS) * gamma[tid];
        sscale[tid] = sc;
        sshift[tid] = beta[tid] - mu * sc;
    }
    __syncthreads();
    int wave = tid >> 6, lane = tid & 63;
    int m = lane & 15, q = lane >> 4;
    int nb = blockIdx.x * 128 + wave * 32;       // this wave's 32 nodes
    unsigned int* hb = &hbufs[wave][0];
    const int xsw = (m & 7) * 4;                 // per-lane XOR swizzle (dwords)

    // build yfrags: y1 = BN1(u) for this wave's 2 strips, direct from global
    short8 yfrag[2][4];
    #pragma unroll
    for (int s = 0; s < 2; ++s) {
        int ng = nb + s * 16 + m;
        if (ng >= NN) ng = NN - 1;
        const uint4* up = (const uint4*)(u2 + (size_t)ng * 64);
        #pragma unroll
        for (int kt = 0; kt < 4; ++kt) {
            uint4 pv = up[kt * 4 + q];
            int c0 = kt * 32 + q * 8;
            float4 sa = *(const float4*)&sscale[c0], sb = *(const float4*)&sscale[c0 + 4];
            float4 ha = *(const float4*)&sshift[c0], hbv = *(const float4*)&sshift[c0 + 4];
            float f0 = __uint_as_float(pv.x << 16)         * sa.x + ha.x;
            float f1 = __uint_as_float(pv.x & 0xffff0000u) * sa.y + ha.y;
            float f2 = __uint_as_float(pv.y << 16)         * sa.z + ha.z;
            float f3 = __uint_as_float(pv.y & 0xffff0000u) * sa.w + ha.w;
            float f4 = __uint_as_float(pv.z << 16)         * sb.x + hbv.x;
            float f5 = __uint_as_float(pv.z & 0xffff0000u) * sb.y + hbv.y;
            float f6 = __uint_as_float(pv.w << 16)         * sb.z + hbv.z;
            float f7 = __uint_as_float(pv.w & 0xffff0000u) * sb.w + hbv.w;
            union { unsigned int u[4]; short8 sv; } yf;
            yf.u[0] = ((unsigned int)f2bfu(f1) << 16) | f2bfu(f0);
            yf.u[1] = ((unsigned int)f2bfu(f3) << 16) | f2bfu(f2);
            yf.u[2] = ((unsigned int)f2bfu(f5) << 16) | f2bfu(f4);
            yf.u[3] = ((unsigned int)f2bfu(f7) << 16) | f2bfu(f6);
            yfrag[s][kt] = yf.sv;
        }
    }

    floatx4 acc2[2][8];
    #pragma unroll
    for (int s = 0; s < 2; ++s)
        #pragma unroll
        for (int t = 0; t < 8; ++t) acc2[s][t] = (floatx4){0.f, 0.f, 0.f, 0.f};

    const uint4* w1g = (const uint4*)w1t;   // row n: 16 uint4
    const uint4* w2g = (const uint4*)w2t;   // row n: 64 uint4

    // prologue: prefetch chunk 0 weights into registers
    uint4 pre1[2], pre2[2];
    #pragma unroll
    for (int it = 0; it < 2; ++it) {
        int i1 = tid + it * 256 * 2;                 // sw1 staging: 1024 uint4 = 4 per thread;
        int i1b = i1 + 256;                          // handled as 2x2 to keep reg count tame
        (void)i1b;
    }
    // 4 uint4 each for sw1 and sw2 per thread (as before), held in regs:
    uint4 p1[4], p2[4];
    #pragma unroll
    for (int it = 0; it < 4; ++it) {
        int i = tid + it * 256;
        p1[it] = w1g[(size_t)(0 * 64 + (i >> 4)) * 16 + (i & 15)];
        p2[it] = w2g[(size_t)(i >> 3) * 64 + 0 * 8 + (i & 7)];
    }

    for (int c = 0; c < 8; ++c) {
        __syncthreads();                     // previous iteration's readers done with sw
        #pragma unroll
        for (int it = 0; it < 4; ++it) {     // regs -> LDS (swizzled)
            int i = tid + it * 256;
            int j = i >> 4, s4 = i & 15;
            *(uint4*)&sw1[j * 64 + ((s4 * 4) ^ ((j & 7) * 4))] = p1[it];
            int n = i >> 3, s8 = i & 7;
            *(uint4*)&sw2[n * 32 + ((s8 * 4) ^ ((n & 7) * 4))] = p2[it];
        }
        __syncthreads();
        if (c < 7) {                          // issue next chunk's loads; latency hides under MFMAs
            #pragma unroll
            for (int it = 0; it < 4; ++it) {
                int i = tid + it * 256;
                p1[it] = w1g[(size_t)((c + 1) * 64 + (i >> 4)) * 16 + (i & 15)];
                p2[it] = w2g[(size_t)(i >> 3) * 64 + (c + 1) * 8 + (i & 7)];
            }
        }
        #pragma unroll
        for (int s = 0; s < 2; ++s) {
            // gemm1T: h^T(64 hid x 16 node) for this strip
            floatx4 acc1[4];
            #pragma unroll
            for (int t = 0; t < 4; ++t) acc1[t] = (floatx4){0.f, 0.f, 0.f, 0.f};
            #pragma unroll
            for (int kt = 0; kt < 4; ++kt) {
                #pragma unroll
                for (int t = 0; t < 4; ++t) {
                    short8 wf = *(const short8*)&sw1[(t * 16 + m) * 64 + ((kt * 16 + q * 4) ^ xsw)];
                    acc1[t] = __builtin_amdgcn_mfma_f32_16x16x32_bf16(wf, yfrag[s][kt], acc1[t], 0, 0, 0);
                }
            }
            // relu + bias -> hbuf (lane holds h[node=m][hid=c*64 + t*16 + q*4 + i])
            #pragma unroll
            for (int t = 0; t < 4; ++t) {
                float4 bb = *(const float4*)&b1[c * 64 + t * 16 + q * 4];
                float h0 = fmaxf(acc1[t][0] + bb.x, 0.f);
                float h1 = fmaxf(acc1[t][1] + bb.y, 0.f);
                float h2 = fmaxf(acc1[t][2] + bb.z, 0.f);
                float h3 = fmaxf(acc1[t][3] + bb.w, 0.f);
                uint2 hp;
                hp.x = ((unsigned int)f2bfu(h1) << 16) | f2bfu(h0);
                hp.y = ((unsigned int)f2bfu(h3) << 16) | f2bfu(h2);
                *(uint2*)&hb[m * 32 + ((t * 8 + q * 2) ^ xsw)] = hp;
            }
            // gemm2: acc2 += h(16 node x 64 k) x w2c(64 k x 128 out)
            #pragma unroll
            for (int kt = 0; kt < 2; ++kt) {
                short8 hf = *(const short8*)&hb[m * 32 + ((kt * 16 + q * 4) ^ xsw)];
                #pragma unroll
                for (int t = 0; t < 8; ++t) {
                    short8 wf2 = *(const short8*)&sw2[(t * 16 + m) * 32 + ((kt * 16 + q * 4) ^ xsw)];
                    acc2[s][t] = __builtin_amdgcn_mfma_f32_16x16x32_bf16(hf, wf2, acc2[s][t], 0, 0, 0);
                }
            }
        }
    }
    // epilogue: C acc2[s][t]: node = q*4+i, outcol = t*16+m; v = y1 + ff + b2
    #pragma unroll
    for (int s = 0; s < 2; ++s) {
        #pragma unroll
        for (int t = 0; t < 8; ++t) {
            int col = t * 16 + m;
            float b2v = b2[col];
            float scl = sscale[col], shf = sshift[col];
            #pragma unroll
            for (int i = 0; i < 4; ++i) {
                int ng = nb + s * 16 + q * 4 + i;
                if (ng < NN) {
                    unsigned int pv = u2[(size_t)ng * 64 + (col >> 1)];
                    float uval = (col & 1) ? __uint_as_float(pv & 0xffff0000u)
                                           : __uint_as_float(pv << 16);
                    v[(size_t)ng * DIM + col] = acc2[s][t][i] + b2v + (uval * scl + shf);
                }
            }
        }
    }
}

// ---------------- final BN2 in place on v (fp32, in d_out) ----------------
__global__ void k_final(float* buf, const float* __restrict__ stats2,
                        const float* __restrict__ gamma,
                        const float* __restrict__ beta) {
    __shared__ float ssc[DIM], ssh[DIM];
    int t = threadIdx.x;
    if (t < DIM) {
        float mu  = stats2[t] * (1.0f / NN);
        float var = stats2[DIM + t] * (1.0f / NN) - mu * mu;
        float rsg = rsqrtf(var + BN_EPS) * gamma[t];
        ssc[t] = rsg;
        ssh[t] = beta[t] - mu * rsg;
    }
    __syncthreads();
    const int total = NN * DIM / 4;   // float4s
    float4* b4 = (float4*)buf;
    for (int i = blockIdx.x * blockDim.x + t; i < total; i += gridDim.x * blockDim.x) {
        float4 val = b4[i];
        int c = (i * 4) & (DIM - 1);
        val.x = val.x * ssc[c]     + ssh[c];
        val.y = val.y * ssc[c + 1] + ssh[c + 1];
        val.z = val.z * ssc[c + 2] + ssh[c + 2];
        val.w = val.w * ssc[c + 3] + ssh[c + 3];
        b4[i] = val;
    }
}

extern "C" void kernel_launch(void* const* d_in, const int* in_sizes, int n_in,
                              void* d_out, int out_size, void* d_ws, size_t ws_size,
                              hipStream_t stream) {
    const float* x     = (const float*)d_in[0];
    const int*   ei    = (const int*)d_in[1];
    const float* W     = (const float*)d_in[2];
    const float* b     = (const float*)d_in[3];
    const float* gamma = (const float*)d_in[4];
    const float* beta  = (const float*)d_in[5];
    const float* w1    = (const float*)d_in[6];
    const float* b1    = (const float*)d_in[7];
    const float* w2    = (const float*)d_in[8];
    const float* b2    = (const float*)d_in[9];

    // workspace bump allocator (~26.5 MB), 256B-aligned regions
    char* p = (char*)d_ws;
    auto alloc = [&](size_t bytes) { char* r = p; p += (bytes + 255) & ~(size_t)255; return r; };
    unsigned int*   u     = (unsigned int*)alloc((size_t)NN * DIM * 2);   // u = x + h, bf16 packed
    int*            cnt   = (int*)alloc((size_t)NN * 4);
    int*            offs  = (int*)alloc((size_t)(NN + 1) * 4);
    float*          dinv  = (float*)alloc((size_t)NN * 4);
    int*            bsum  = (int*)alloc(128 * 4);
    int*            bincur = (int*)alloc((size_t)NBIN * 4);
    unsigned short* wt    = (unsigned short*)alloc((size_t)DIM * DIM * 2);
    unsigned short* w1t   = (unsigned short*)alloc((size_t)HID * DIM * 2);
    unsigned short* w2t   = (unsigned short*)alloc((size_t)HID * DIM * 2);
    float*          stats = (float*)alloc(512 * 4);

    // d_out (51.2 MB fp32) doubles as scratch during the graph phase:
    //   [0, 13.82MB)     recs (uint, NBIN*CAP) — fixed-capacity bin records; dead after
    //                    k_fill2; region then overwritten by k_gemm1's xw [0, 25.6MB)
    //   [25.6, 38.4MB)   srcs (int, NE)
    // All dead before k_ffx writes v over [0, 51.2MB).
    unsigned short* xw   = (unsigned short*)d_out;
    unsigned int*   recs = (unsigned int*)d_out;
    int*            srcs = (int*)((char*)d_out + (size_t)NN * DIM * 2);
    float*          v    = (float*)d_out;

    const int* esrc = ei;
    const int* edst = ei + NE;
    const int nblk = (NN + 1023) / 1024;   // 98
    const int n1blk = (NE + TILE - 1) / TILE;   // 1563

    k_init<<<2, 256, 0, stream>>>(bincur, stats);
    k_fill1<<<n1blk, 256, 0, stream>>>(esrc, edst, bincur, recs);
    k_cnt<<<NBIN, 256, 0, stream>>>(recs, bincur, cnt);
    k_scanA<<<nblk, 1024, 0, stream>>>(cnt, offs, bsum, dinv);
    k_scanB<<<1, 128, 0, stream>>>(bsum, offs, nblk);
    k_scanC<<<(NN + 255) / 256, 256, 0, stream>>>(offs, bsum);
    k_fill2<<<NBIN, 256, 0, stream>>>(recs, bincur, offs, srcs);
    k_wt<<<(DIM * DIM + 255) / 256, 256, 0, stream>>>(W, wt);
    k_prep<<<(HID * DIM + 255) / 256, 256, 0, stream>>>(w1, w2, w1t, w2t);
    k_gemm1<<<(NN + 63) / 64, 256, 0, stream>>>(x, wt, dinv, xw);
    k_aggregate<<<(NN + 3) / 4, 256, 0, stream>>>((const unsigned int*)xw, offs, srcs, dinv, x, b, u);
    k_stats<<<512, 256, 0, stream>>>(u, stats);
    k_ffx<<<(NN + 127) / 128, 256, 0, stream>>>(u, stats, gamma, beta, w1t, b1, w2t, b2, v);
    k_stats2<<<512, 256, 0, stream>>>((const float2*)v, stats + 256);
    k_final<<<2048, 256, 0, stream>>>((float*)d_out, stats + 256, gamma, beta);
}

// Round 13
// 588.973 us; speedup vs baseline: 1.2172x; 1.2172x over previous
//
#include <hip/hip_runtime.h>
#include <hip/hip_bf16.h>
#include <stdint.h>

#define NN 100000
#define NE 3200000
#define DIM 128
#define HID 512
#define BN_EPS 1e-5f
#define NBIN 128     // dst bins for 2-pass CSR build (fine enough for LDS cursors in fill2)
#define NPBIN 784    // nodes per bin (128*784 = 100352 >= NN); d_local < 784 fits 10 bits
#define TILE 2048    // edges per block-tile in pass 1 (8 per thread)
#define CAP 27000    // fixed bin capacity: mean 25088, sigma~158 -> 12-sigma slack

typedef short short8 __attribute__((ext_vector_type(8)));
typedef float floatx4 __attribute__((ext_vector_type(4)));

__device__ __forceinline__ float bfu2f(unsigned short u) {
    return __uint_as_float(((unsigned int)u) << 16);
}
__device__ __forceinline__ unsigned short f2bfu(float f) {
    union { __hip_bfloat16 h; unsigned short u; } cv;
    cv.h = __float2bfloat16(f);
    return cv.u;
}

// ---------------- init: bin cursors (fixed-capacity regions) + BN stat accumulators ----------------
__global__ void k_init(int* __restrict__ bincur, float* __restrict__ stats) {
    int i = blockIdx.x * 256 + threadIdx.x;
    if (i < NBIN) bincur[i] = i * CAP;
    if (i < 512) stats[i] = 0.f;   // [0..127]=sum1,[128..255]=sq1,[256..383]=sum2,[384..511]=sq2
}

// ---------------- CSR build pass 1: LDS multi-split into 128 FIXED-CAPACITY dst-bin regions ----
__global__ __launch_bounds__(256) void k_fill1(const int* __restrict__ src, const int* __restrict__ dst,
                                               int* __restrict__ bincur, unsigned int* __restrict__ recs) {
    __shared__ int lhist[NBIN], lbase[NBIN], gbase[NBIN];
    __shared__ unsigned int lrec[TILE];
    int tid = threadIdx.x;
    int tbase = blockIdx.x * TILE;
    if (tid < NBIN) lhist[tid] = 0;
    __syncthreads();
    unsigned int myrec[8];
    int mybin[8], myrank[8];
    #pragma unroll
    for (int j = 0; j < 8; ++j) {
        int e = tbase + j * 256 + tid;
        mybin[j] = -1;
        if (e < NE) {
            int d = __builtin_nontemporal_load(dst + e);
            int s = __builtin_nontemporal_load(src + e);
            int b = d / NPBIN;            // 0..127
            myrec[j] = (unsigned)s | ((unsigned)(d - b * NPBIN) << 17);
            mybin[j] = b;
            myrank[j] = atomicAdd(&lhist[b], 1);
        }
    }
    __syncthreads();
    if (tid == 0) {                        // exclusive scan of 128 bin counts
        int run = 0;
        #pragma unroll
        for (int b = 0; b < NBIN; ++b) { lbase[b] = run; run += lhist[b]; }
    }
    __syncthreads();
    if (tid < NBIN) gbase[tid] = atomicAdd(&bincur[tid], lhist[tid]);
    __syncthreads();
    #pragma unroll
    for (int j = 0; j < 8; ++j)
        if (mybin[j] >= 0) lrec[lbase[mybin[j]] + myrank[j]] = myrec[j];
    __syncthreads();
    int total = lbase[NBIN - 1] + lhist[NBIN - 1];
    for (int i = tid; i < total; i += 256) {
        int b = 0;                         // largest b with lbase[b] <= i (lbase monotone)
        #pragma unroll
        for (int st = NBIN / 2; st > 0; st >>= 1)
            if (b + st < NBIN && lbase[b + st] <= i) b += st;
        int p = gbase[b] + (i - lbase[b]);
        if (p < (b + 1) * CAP) recs[p] = lrec[i];   // capacity guard (12-sigma slack)
    }
}

// ---------------- per-bin LDS histogram -> cnt, one block per bin, NO global atomics --------
__global__ __launch_bounds__(256) void k_cnt(const unsigned int* __restrict__ recs,
                                             const int* __restrict__ bincur,
                                             int* __restrict__ cnt) {
    __shared__ int lhist[NPBIN];
    int b = blockIdx.x;
    int tid = threadIdx.x;
    for (int i = tid; i < NPBIN; i += 256) lhist[i] = 0;
    __syncthreads();
    int start = b * CAP;
    int end = bincur[b];
    if (end > start + CAP) end = start + CAP;
    if (end < start) end = start;
    for (int i = start + tid; i < end; i += 256) {
        unsigned int r = __builtin_nontemporal_load(recs + i);
        int dl = (int)(r >> 17);
        if (dl < NPBIN) atomicAdd(&lhist[dl], 1);
    }
    __syncthreads();
    for (int i = tid; i < NPBIN; i += 256) {
        int n = b * NPBIN + i;
        if (n < NN) cnt[n] = lhist[i];
    }
}

// ---------------- scan stage A: per-block (1024-wide) local exclusive scan + block sums + dinv ----
__global__ __launch_bounds__(1024) void k_scanA(const int* __restrict__ cnt, int* __restrict__ offs,
                                                int* __restrict__ bsum, float* __restrict__ dinv) {
    __shared__ int wsum[16];
    int t = threadIdx.x;          // 1024 threads = 16 waves
    int lane = t & 63, wid = t >> 6;
    int i = blockIdx.x * 1024 + t;
    int v = (i < NN) ? cnt[i] : 0;
    int incl = v;
    #pragma unroll
    for (int off = 1; off < 64; off <<= 1) {
        int y = __shfl_up(incl, off, 64);
        if (lane >= off) incl += y;
    }
    if (lane == 63) wsum[wid] = incl;
    __syncthreads();
    if (wid == 0) {
        int wv = (lane < 16) ? wsum[lane] : 0;
        int wincl = wv;
        #pragma unroll
        for (int off = 1; off < 16; off <<= 1) {
            int y = __shfl_up(wincl, off, 64);
            if (lane >= off) wincl += y;
        }
        if (lane < 16) wsum[lane] = wincl - wv;   // exclusive wave offsets
    }
    __syncthreads();
    int excl = wsum[wid] + incl - v;              // block-local exclusive
    if (i < NN) {
        offs[i] = excl;
        dinv[i] = rsqrtf((float)(v + 1));         // deg includes self-loop
    }
    if (t == 1023) bsum[blockIdx.x] = excl + v;   // block total
}

// ---------------- scan stage B: single block scans the 98 block sums ----------------
__global__ __launch_bounds__(128) void k_scanB(int* __restrict__ bsum, int* __restrict__ offs, int nblk) {
    int t = threadIdx.x;   // 128 >= nblk; two waves, use wave 0 only
    if (t < 64) {
        int v = (t < nblk) ? bsum[t] : 0;
        int v2 = (t + 64 < nblk) ? bsum[t + 64] : 0;
        int incl = v;
        #pragma unroll
        for (int off = 1; off < 64; off <<= 1) {
            int y = __shfl_up(incl, off, 64);
            if (t >= off) incl += y;
        }
        int tot0 = __shfl(incl, 63, 64);
        int incl2 = v2;
        #pragma unroll
        for (int off = 1; off < 64; off <<= 1) {
            int y = __shfl_up(incl2, off, 64);
            if (t >= off) incl2 += y;
        }
        if (t < nblk) bsum[t] = incl - v;                      // exclusive
        if (t + 64 < nblk) bsum[t + 64] = tot0 + incl2 - v2;
        if (t == 63) offs[NN] = tot0 + __shfl(incl2, 63, 64);  // grand total
    }
}

// ---------------- scan stage C: add block bases ----------------
__global__ void k_scanC(int* __restrict__ offs, const int* __restrict__ bsum) {
    int i = blockIdx.x * 256 + threadIdx.x;
    if (i < NN) offs[i] += bsum[i >> 10];
}

// ---------------- CSR build pass 2: per-bin scatter with LDS cursors, ZERO global atomics ----
__global__ __launch_bounds__(256) void k_fill2(const unsigned int* __restrict__ recs,
                                               const int* __restrict__ bincur,
                                               const int* __restrict__ offs,
                                               int* __restrict__ srcs) {
    __shared__ int loffs[NPBIN], lcur[NPBIN];
    int b = blockIdx.x;
    int tid = threadIdx.x;
    for (int i = tid; i < NPBIN; i += 256) {
        int n = b * NPBIN + i;
        loffs[i] = (n <= NN) ? offs[n] : NE;
        lcur[i] = 0;
    }
    __syncthreads();
    int start = b * CAP;
    int end = bincur[b];
    if (end > start + CAP) end = start + CAP;
    if (end < start) end = start;
    for (int i = start + tid; i < end; i += 256) {
        unsigned int r = __builtin_nontemporal_load(recs + i);
        int s = (int)(r & 0x1FFFFu);
        int dl = (int)(r >> 17);
        if (dl < NPBIN) {
            int p = loffs[dl] + atomicAdd(&lcur[dl], 1);
            if ((unsigned)p < NE) srcs[p] = s;
        }
    }
}

// ---------------- transpose W (fp32) -> bf16 wt[n][k] ----------------
__global__ void k_wt(const float* __restrict__ W, unsigned short* __restrict__ wt) {
    int i = blockIdx.x * 256 + threadIdx.x;
    if (i < DIM * DIM) {
        int k = i >> 7, n = i & 127;
        wt[n * DIM + k] = f2bfu(W[k * DIM + n]);
    }
}

// ---------------- prep FF weights: w1t[n=512][k=128], w2t[n=128][k=512] (bf16, transposed) -------
__global__ void k_prep(const float* __restrict__ w1, const float* __restrict__ w2,
                       unsigned short* __restrict__ w1t, unsigned short* __restrict__ w2t) {
    int i = blockIdx.x * 256 + threadIdx.x;
    if (i < HID * DIM) {
        int n1 = i >> 7, k1 = i & 127;           // w1t[n1*128+k1] = w1[k1*512+n1]
        w1t[i] = f2bfu(w1[k1 * HID + n1]);
        int n2 = i & 127, k2 = i >> 7;           // w2t[n2*512+k2] = w2[k2*DIM+n2]
        w2t[n2 * HID + k2] = f2bfu(w2[k2 * DIM + n2]);
    }
}

// ---------------- xw' = dinv .* (bf16(x) @ bf16(W)) via MFMA; dinv folded ----------------
__global__ __launch_bounds__(256) void k_gemm1(const float* __restrict__ x,
                                               const unsigned short* __restrict__ wt,
                                               const float* __restrict__ dinv,
                                               unsigned short* __restrict__ xw) {
    int wave = threadIdx.x >> 6;
    int lane = threadIdx.x & 63;
    int row0 = blockIdx.x * 64 + wave * 16;
    int arow = row0 + (lane & 15);
    if (arow >= NN) arow = NN - 1;        // clamp; stores are guarded
    int kbase = (lane >> 4) * 8;
    const float* xr = x + (size_t)arow * DIM;
    short8 afrag[4];
    #pragma unroll
    for (int kt = 0; kt < 4; ++kt) {
        float4 f0 = *(const float4*)(xr + kt * 32 + kbase);
        float4 f1 = *(const float4*)(xr + kt * 32 + kbase + 4);
        short8 a;
        a[0] = (short)f2bfu(f0.x); a[1] = (short)f2bfu(f0.y);
        a[2] = (short)f2bfu(f0.z); a[3] = (short)f2bfu(f0.w);
        a[4] = (short)f2bfu(f1.x); a[5] = (short)f2bfu(f1.y);
        a[6] = (short)f2bfu(f1.z); a[7] = (short)f2bfu(f1.w);
        afrag[kt] = a;                     // A[m=lane&15][k=quad*8+j]
    }
    int crow = row0 + (lane >> 4) * 4;
    float dv[4];
    #pragma unroll
    for (int i = 0; i < 4; ++i) {
        int r = crow + i;
        dv[i] = dinv[r < NN ? r : NN - 1];
    }
    #pragma unroll
    for (int ct = 0; ct < 8; ++ct) {
        int ncol = ct * 16 + (lane & 15);
        const short* wr = (const short*)wt + (size_t)ncol * DIM;
        floatx4 acc = {0.f, 0.f, 0.f, 0.f};
        #pragma unroll
        for (int kt = 0; kt < 4; ++kt) {
            short8 bfrag = *(const short8*)(wr + kt * 32 + kbase); // B[k=quad*8+j][n=lane&15]
            acc = __builtin_amdgcn_mfma_f32_16x16x32_bf16(afrag[kt], bfrag, acc, 0, 0, 0);
        }
        #pragma unroll
        for (int i = 0; i < 4; ++i) {
            int r = crow + i;                  // C: row=(lane>>4)*4+reg, col=lane&15
            if (r < NN) xw[(size_t)r * DIM + ct * 16 + (lane & 15)] = f2bfu(acc[i] * dv[i]);
        }
    }
}

// ---------------- aggregate v4: register-blocked indices + QUAD edge pairing ----------------
__global__ __launch_bounds__(256) void k_aggregate(const unsigned int* __restrict__ xw2,
                                                   const int* __restrict__ offs,
                                                   const int* __restrict__ srcs,
                                                   const float* __restrict__ dinv,
                                                   const float* __restrict__ x,
                                                   const float* __restrict__ bias,
                                                   unsigned int* __restrict__ u) {
    int node = blockIdx.x * 4 + (threadIdx.x >> 6);
    if (node >= NN) return;
    int lane = threadIdx.x & 63;
    int qt = lane >> 4;              // edge slot within quad (0..3)
    int ql = lane & 15;              // handles cols 8*ql .. 8*ql+7
    int beg = offs[node], end = offs[node + 1];
    beg = max(0, min(beg, NE));
    end = max(beg, min(end, NE));
    int ne = end - beg;
    float a[8];
    #pragma unroll
    for (int j = 0; j < 8; ++j) a[j] = 0.f;
    const uint4* xw16 = (const uint4*)xw2;       // row = 16 uint4 (256B)
    for (int base = 0; base < ne; base += 64) {
        int rem = ne - base;
        if (rem > 64) rem = 64;
        int sidx = (lane < rem) ? srcs[beg + base + lane] : 0;
        #pragma unroll 4
        for (int i = 0; i < rem; i += 4) {
            int want = i + qt;
            int s = __builtin_amdgcn_ds_bpermute(want << 2, sidx);
            if (want < rem) {
                if ((unsigned)s >= NN) s = 0;
                uint4 pk = xw16[(size_t)s * 16 + ql];
                a[0] += __uint_as_float(pk.x << 16);
                a[1] += __uint_as_float(pk.x & 0xffff0000u);
                a[2] += __uint_as_float(pk.y << 16);
                a[3] += __uint_as_float(pk.y & 0xffff0000u);
                a[4] += __uint_as_float(pk.z << 16);
                a[5] += __uint_as_float(pk.z & 0xffff0000u);
                a[6] += __uint_as_float(pk.w << 16);
                a[7] += __uint_as_float(pk.w & 0xffff0000u);
            }
        }
    }
    // combine the 4 quad partial sums (all lanes end with the full sum)
    #pragma unroll
    for (int j = 0; j < 8; ++j) {
        a[j] += __shfl_xor(a[j], 16, 64);
        a[j] += __shfl_xor(a[j], 32, 64);
    }
    if (qt == 0) {                   // lanes 0..15 write the 256B row
        uint4 ps = xw16[(size_t)node * 16 + ql];
        float di = dinv[node];
        const float* xr = x + (size_t)node * DIM + ql * 8;
        float4 xv0 = *(const float4*)xr;
        float4 xv1 = *(const float4*)(xr + 4);
        float4 bv0 = *(const float4*)(bias + ql * 8);
        float4 bv1 = *(const float4*)(bias + ql * 8 + 4);
        float o0 = xv0.x + bv0.x + di * (a[0] + __uint_as_float(ps.x << 16));
        float o1 = xv0.y + bv0.y + di * (a[1] + __uint_as_float(ps.x & 0xffff0000u));
        float o2 = xv0.z + bv0.z + di * (a[2] + __uint_as_float(ps.y << 16));
        float o3 = xv0.w + bv0.w + di * (a[3] + __uint_as_float(ps.y & 0xffff0000u));
        float o4 = xv1.x + bv1.x + di * (a[4] + __uint_as_float(ps.z << 16));
        float o5 = xv1.y + bv1.y + di * (a[5] + __uint_as_float(ps.z & 0xffff0000u));
        float o6 = xv1.z + bv1.z + di * (a[6] + __uint_as_float(ps.w << 16));
        float o7 = xv1.w + bv1.w + di * (a[7] + __uint_as_float(ps.w & 0xffff0000u));
        uint4 pk;
        pk.x = ((unsigned int)f2bfu(o1) << 16) | (unsigned int)f2bfu(o0);
        pk.y = ((unsigned int)f2bfu(o3) << 16) | (unsigned int)f2bfu(o2);
        pk.z = ((unsigned int)f2bfu(o5) << 16) | (unsigned int)f2bfu(o4);
        pk.w = ((unsigned int)f2bfu(o7) << 16) | (unsigned int)f2bfu(o6);
        ((uint4*)u)[(size_t)node * 16 + ql] = pk;
    }
}

// ---------------- BN1 stats: per-column sum & sumsq of u (bf16) ----------------
__global__ void k_stats(const unsigned int* __restrict__ u2, float* __restrict__ stats) {
    int t = threadIdx.x;            // 256
    int c = t & 63, g = t >> 6;     // uint index c -> bf16 cols 2c, 2c+1
    float s0 = 0.f, q0 = 0.f, s1 = 0.f, q1 = 0.f;
    for (int r = blockIdx.x * 4 + g; r < NN; r += gridDim.x * 4) {
        unsigned int pv = u2[(size_t)r * 64 + c];
        float x0 = __uint_as_float(pv << 16);
        float x1 = __uint_as_float(pv & 0xffff0000u);
        s0 += x0; q0 += x0 * x0; s1 += x1; q1 += x1 * x1;
    }
    __shared__ float A[256], B[256], C[256], D2[256];
    A[t] = s0; B[t] = q0; C[t] = s1; D2[t] = q1;
    __syncthreads();
    if (t < 64) {
        float rs0 = A[t] + A[t + 64] + A[t + 128] + A[t + 192];
        float rq0 = B[t] + B[t + 64] + B[t + 128] + B[t + 192];
        float rs1 = C[t] + C[t + 64] + C[t + 128] + C[t + 192];
        float rq1 = D2[t] + D2[t + 64] + D2[t + 128] + D2[t + 192];
        atomicAdd(&stats[2 * c],           rs0);
        atomicAdd(&stats[2 * c + 1],       rs1);
        atomicAdd(&stats[DIM + 2 * c],     rq0);
        atomicAdd(&stats[DIM + 2 * c + 1], rq1);
    }
}

// ---------------- BN2 stats: per-column sum & sumsq of v (fp32) ----------------
__global__ void k_stats2(const float2* __restrict__ v2, float* __restrict__ stats) {
    int t = threadIdx.x;            // 256
    int c = t & 63, g = t >> 6;     // float2 index c -> cols 2c, 2c+1
    float s0 = 0.f, q0 = 0.f, s1 = 0.f, q1 = 0.f;
    for (int r = blockIdx.x * 4 + g; r < NN; r += gridDim.x * 4) {
        float2 pv = v2[(size_t)r * 64 + c];
        s0 += pv.x; q0 += pv.x * pv.x; s1 += pv.y; q1 += pv.y * pv.y;
    }
    __shared__ float A[256], B[256], C[256], D2[256];
    A[t] = s0; B[t] = q0; C[t] = s1; D2[t] = q1;
    __syncthreads();
    if (t < 64) {
        float rs0 = A[t] + A[t + 64] + A[t + 128] + A[t + 192];
        float rq0 = B[t] + B[t + 64] + B[t + 128] + B[t + 192];
        float rs1 = C[t] + C[t + 64] + C[t + 128] + C[t + 192];
        float rq1 = D2[t] + D2[t + 64] + D2[t + 128] + D2[t + 192];
        atomicAdd(&stats[2 * c],           rs0);
        atomicAdd(&stats[2 * c + 1],       rs1);
        atomicAdd(&stats[DIM + 2 * c],     rq0);
        atomicAdd(&stats[DIM + 2 * c + 1], rq1);
    }
}

// ---------------- fused FF v5: 8 waves / 256 nodes per block ----------------
// r12 lesson: register double-buffer spilled (VGPR 136, occ 8.8%, +32MB scratch traffic) —
// reverted to direct staging. Instead attack the staging:compute RATIO: the 32KB/chunk weight
// stage is a per-block fixed cost; 256 nodes/block (8 waves) halves staged bytes per node and
// doubles the compute each stage amortizes over. LDS 49KB, VGPR ~104 -> 2 blocks/CU (16 waves).
__global__ __launch_bounds__(512) void k_ffx(const unsigned int* __restrict__ u2,
                                             const float* __restrict__ stats1,
                                             const float* __restrict__ gamma,
                                             const float* __restrict__ beta,
                                             const unsigned short* __restrict__ w1t,
                                             const float* __restrict__ b1,
                                             const unsigned short* __restrict__ w2t,
                                             const float* __restrict__ b2,
                                             float* __restrict__ v) {
    __shared__ __align__(16) float sscale[DIM], sshift[DIM];
    __shared__ __align__(16) unsigned int sw1[64 * 64];       // 16KB: w1 chunk [64 hid][128 k bf16]
    __shared__ __align__(16) unsigned int sw2[128 * 32];      // 16KB: w2 chunk [128 out][64 k bf16]
    __shared__ __align__(16) unsigned int hbufs[8][16 * 32];  // 16KB: per-wave h strip
    int tid = threadIdx.x;
    if (tid < DIM) {
        float mu  = stats1[tid] * (1.0f / NN);
        float var = stats1[DIM + tid] * (1.0f / NN) - mu * mu;
        float sc = rsqrtf(var + BN_EPS) * gamma[tid];
        sscale[tid] = sc;
        sshift[tid] = beta[tid] - mu * sc;
    }
    __syncthreads();
    int wave = tid >> 6, lane = tid & 63;        // wave 0..7
    int m = lane & 15, q = lane >> 4;
    int nb = blockIdx.x * 256 + wave * 32;       // this wave's 32 nodes
    unsigned int* hb = &hbufs[wave][0];
    const int xsw = (m & 7) * 4;                 // per-lane XOR swizzle (dwords)

    // build yfrags: y1 = BN1(u) for this wave's 2 strips, direct from global
    short8 yfrag[2][4];
    #pragma unroll
    for (int s = 0; s < 2; ++s) {
        int ng = nb + s * 16 + m;
        if (ng >= NN) ng = NN - 1;
        const uint4* up = (const uint4*)(u2 + (size_t)ng * 64);
        #pragma unroll
        for (int kt = 0; kt < 4; ++kt) {
            uint4 pv = up[kt * 4 + q];
            int c0 = kt * 32 + q * 8;
            float4 sa = *(const float4*)&sscale[c0], sb = *(const float4*)&sscale[c0 + 4];
            float4 ha = *(const float4*)&sshift[c0], hbv = *(const float4*)&sshift[c0 + 4];
            float f0 = __uint_as_float(pv.x << 16)         * sa.x + ha.x;
            float f1 = __uint_as_float(pv.x & 0xffff0000u) * sa.y + ha.y;
            float f2 = __uint_as_float(pv.y << 16)         * sa.z + ha.z;
            float f3 = __uint_as_float(pv.y & 0xffff0000u) * sa.w + ha.w;
            float f4 = __uint_as_float(pv.z << 16)         * sb.x + hbv.x;
            float f5 = __uint_as_float(pv.z & 0xffff0000u) * sb.y + hbv.y;
            float f6 = __uint_as_float(pv.w << 16)         * sb.z + hbv.z;
            float f7 = __uint_as_float(pv.w & 0xffff0000u) * sb.w + hbv.w;
            union { unsigned int u[4]; short8 sv; } yf;
            yf.u[0] = ((unsigned int)f2bfu(f1) << 16) | f2bfu(f0);
            yf.u[1] = ((unsigned int)f2bfu(f3) << 16) | f2bfu(f2);
            yf.u[2] = ((unsigned int)f2bfu(f5) << 16) | f2bfu(f4);
            yf.u[3] = ((unsigned int)f2bfu(f7) << 16) | f2bfu(f6);
            yfrag[s][kt] = yf.sv;
        }
    }

    floatx4 acc2[2][8];
    #pragma unroll
    for (int s = 0; s < 2; ++s)
        #pragma unroll
        for (int t = 0; t < 8; ++t) acc2[s][t] = (floatx4){0.f, 0.f, 0.f, 0.f};

    const uint4* w1g = (const uint4*)w1t;   // row n: 16 uint4
    const uint4* w2g = (const uint4*)w2t;   // row n: 64 uint4

    for (int c = 0; c < 8; ++c) {
        __syncthreads();                     // protect sw from previous iteration's readers
        #pragma unroll
        for (int it = 0; it < 2; ++it) {     // stage w1c: 64 rows x 16 uint4 (512 threads)
            int i = tid + it * 512;
            int j = i >> 4, s4 = i & 15;
            uint4 val = w1g[(size_t)(c * 64 + j) * 16 + s4];
            *(uint4*)&sw1[j * 64 + ((s4 * 4) ^ ((j & 7) * 4))] = val;
        }
        #pragma unroll
        for (int it = 0; it < 2; ++it) {     // stage w2c: 128 rows x 8 uint4 (k-window c*64)
            int i = tid + it * 512;
            int n = i >> 3, s4 = i & 7;
            uint4 val = w2g[(size_t)n * 64 + c * 8 + s4];
            *(uint4*)&sw2[n * 32 + ((s4 * 4) ^ ((n & 7) * 4))] = val;
        }
        __syncthreads();
        #pragma unroll
        for (int s = 0; s < 2; ++s) {
            // gemm1T: h^T(64 hid x 16 node) for this strip
            floatx4 acc1[4];
            #pragma unroll
            for (int t = 0; t < 4; ++t) acc1[t] = (floatx4){0.f, 0.f, 0.f, 0.f};
            #pragma unroll
            for (int kt = 0; kt < 4; ++kt) {
                #pragma unroll
                for (int t = 0; t < 4; ++t) {
                    short8 wf = *(const short8*)&sw1[(t * 16 + m) * 64 + ((kt * 16 + q * 4) ^ xsw)];
                    acc1[t] = __builtin_amdgcn_mfma_f32_16x16x32_bf16(wf, yfrag[s][kt], acc1[t], 0, 0, 0);
                }
            }
            // relu + bias -> hbuf (lane holds h[node=m][hid=c*64 + t*16 + q*4 + i])
            #pragma unroll
            for (int t = 0; t < 4; ++t) {
                float4 bb = *(const float4*)&b1[c * 64 + t * 16 + q * 4];
                float h0 = fmaxf(acc1[t][0] + bb.x, 0.f);
                float h1 = fmaxf(acc1[t][1] + bb.y, 0.f);
                float h2 = fmaxf(acc1[t][2] + bb.z, 0.f);
                float h3 = fmaxf(acc1[t][3] + bb.w, 0.f);
                uint2 hp;
                hp.x = ((unsigned int)f2bfu(h1) << 16) | f2bfu(h0);
                hp.y = ((unsigned int)f2bfu(h3) << 16) | f2bfu(h2);
                *(uint2*)&hb[m * 32 + ((t * 8 + q * 2) ^ xsw)] = hp;
            }
            // gemm2: acc2 += h(16 node x 64 k) x w2c(64 k x 128 out)
            #pragma unroll
            for (int kt = 0; kt < 2; ++kt) {
                short8 hf = *(const short8*)&hb[m * 32 + ((kt * 16 + q * 4) ^ xsw)];
                #pragma unroll
                for (int t = 0; t < 8; ++t) {
                    short8 wf2 = *(const short8*)&sw2[(t * 16 + m) * 32 + ((kt * 16 + q * 4) ^ xsw)];
                    acc2[s][t] = __builtin_amdgcn_mfma_f32_16x16x32_bf16(hf, wf2, acc2[s][t], 0, 0, 0);
                }
            }
        }
    }
    // epilogue: C acc2[s][t]: node = q*4+i, outcol = t*16+m; v = y1 + ff + b2
    #pragma unroll
    for (int s = 0; s < 2; ++s) {
        #pragma unroll
        for (int t = 0; t < 8; ++t) {
            int col = t * 16 + m;
            float b2v = b2[col];
            float scl = sscale[col], shf = sshift[col];
            #pragma unroll
            for (int i = 0; i < 4; ++i) {
                int ng = nb + s * 16 + q * 4 + i;
                if (ng < NN) {
                    unsigned int pv = u2[(size_t)ng * 64 + (col >> 1)];
                    float uval = (col & 1) ? __uint_as_float(pv & 0xffff0000u)
                                           : __uint_as_float(pv << 16);
                    v[(size_t)ng * DIM + col] = acc2[s][t][i] + b2v + (uval * scl + shf);
                }
            }
        }
    }
}

// ---------------- final BN2 in place on v (fp32, in d_out) ----------------
__global__ void k_final(float* buf, const float* __restrict__ stats2,
                        const float* __restrict__ gamma,
                        const float* __restrict__ beta) {
    __shared__ float ssc[DIM], ssh[DIM];
    int t = threadIdx.x;
    if (t < DIM) {
        float mu  = stats2[t] * (1.0f / NN);
        float var = stats2[DIM + t] * (1.0f / NN) - mu * mu;
        float rsg = rsqrtf(var + BN_EPS) * gamma[t];
        ssc[t] = rsg;
        ssh[t] = beta[t] - mu * rsg;
    }
    __syncthreads();
    const int total = NN * DIM / 4;   // float4s
    float4* b4 = (float4*)buf;
    for (int i = blockIdx.x * blockDim.x + t; i < total; i += gridDim.x * blockDim.x) {
        float4 val = b4[i];
        int c = (i * 4) & (DIM - 1);
        val.x = val.x * ssc[c]     + ssh[c];
        val.y = val.y * ssc[c + 1] + ssh[c + 1];
        val.z = val.z * ssc[c + 2] + ssh[c + 2];
        val.w = val.w * ssc[c + 3] + ssh[c + 3];
        b4[i] = val;
    }
}

extern "C" void kernel_launch(void* const* d_in, const int* in_sizes, int n_in,
                              void* d_out, int out_size, void* d_ws, size_t ws_size,
                              hipStream_t stream) {
    const float* x     = (const float*)d_in[0];
    const int*   ei    = (const int*)d_in[1];
    const float* W     = (const float*)d_in[2];
    const float* b     = (const float*)d_in[3];
    const float* gamma = (const float*)d_in[4];
    const float* beta  = (const float*)d_in[5];
    const float* w1    = (const float*)d_in[6];
    const float* b1    = (const float*)d_in[7];
    const float* w2    = (const float*)d_in[8];
    const float* b2    = (const float*)d_in[9];

    // workspace bump allocator (~26.5 MB), 256B-aligned regions
    char* p = (char*)d_ws;
    auto alloc = [&](size_t bytes) { char* r = p; p += (bytes + 255) & ~(size_t)255; return r; };
    unsigned int*   u     = (unsigned int*)alloc((size_t)NN * DIM * 2);   // u = x + h, bf16 packed
    int*            cnt   = (int*)alloc((size_t)NN * 4);
    int*            offs  = (int*)alloc((size_t)(NN + 1) * 4);
    float*          dinv  = (float*)alloc((size_t)NN * 4);
    int*            bsum  = (int*)alloc(128 * 4);
    int*            bincur = (int*)alloc((size_t)NBIN * 4);
    unsigned short* wt    = (unsigned short*)alloc((size_t)DIM * DIM * 2);
    unsigned short* w1t   = (unsigned short*)alloc((size_t)HID * DIM * 2);
    unsigned short* w2t   = (unsigned short*)alloc((size_t)HID * DIM * 2);
    float*          stats = (float*)alloc(512 * 4);

    // d_out (51.2 MB fp32) doubles as scratch during the graph phase:
    //   [0, 13.82MB)     recs (uint, NBIN*CAP) — fixed-capacity bin records; dead after
    //                    k_fill2; region then overwritten by k_gemm1's xw [0, 25.6MB)
    //   [25.6, 38.4MB)   srcs (int, NE)
    // All dead before k_ffx writes v over [0, 51.2MB).
    unsigned short* xw   = (unsigned short*)d_out;
    unsigned int*   recs = (unsigned int*)d_out;
    int*            srcs = (int*)((char*)d_out + (size_t)NN * DIM * 2);
    float*          v    = (float*)d_out;

    const int* esrc = ei;
    const int* edst = ei + NE;
    const int nblk = (NN + 1023) / 1024;   // 98
    const int n1blk = (NE + TILE - 1) / TILE;   // 1563

    k_init<<<2, 256, 0, stream>>>(bincur, stats);
    k_fill1<<<n1blk, 256, 0, stream>>>(esrc, edst, bincur, recs);
    k_cnt<<<NBIN, 256, 0, stream>>>(recs, bincur, cnt);
    k_scanA<<<nblk, 1024, 0, stream>>>(cnt, offs, bsum, dinv);
    k_scanB<<<1, 128, 0, stream>>>(bsum, offs, nblk);
    k_scanC<<<(NN + 255) / 256, 256, 0, stream>>>(offs, bsum);
    k_fill2<<<NBIN, 256, 0, stream>>>(recs, bincur, offs, srcs);
    k_wt<<<(DIM * DIM + 255) / 256, 256, 0, stream>>>(W, wt);
    k_prep<<<(HID * DIM + 255) / 256, 256, 0, stream>>>(w1, w2, w1t, w2t);
    k_gemm1<<<(NN + 63) / 64, 256, 0, stream>>>(x, wt, dinv, xw);
    k_aggregate<<<(NN + 3) / 4, 256, 0, stream>>>((const unsigned int*)xw, offs, srcs, dinv, x, b, u);
    k_stats<<<512, 256, 0, stream>>>(u, stats);
    k_ffx<<<(NN + 255) / 256, 512, 0, stream>>>(u, stats, gamma, beta, w1t, b1, w2t, b2, v);
    k_stats2<<<512, 256, 0, stream>>>((const float2*)v, stats + 256);
    k_final<<<2048, 256, 0, stream>>>((float*)d_out, stats + 256, gamma, beta);
}

// Round 14
// 556.482 us; speedup vs baseline: 1.2883x; 1.0584x over previous
//
#include <hip/hip_runtime.h>
#include <hip/hip_bf16.h>
#include <stdint.h>

#define NN 100000
#define NE 3200000
#define DIM 128
#define HID 512
#define BN_EPS 1e-5f
#define NBIN 128     // dst bins for 2-pass CSR build (fine enough for LDS cursors in fill2)
#define NPBIN 784    // nodes per bin (128*784 = 100352 >= NN); d_local < 784 fits 10 bits
#define TILE 2048    // edges per block-tile in pass 1 (8 per thread)
#define CAP 27000    // fixed bin capacity: mean 25088, sigma~158 -> 12-sigma slack

// k_ffx dynamic-LDS layout (dword offsets): 2x dbuf weights + per-wave hbufs + BN consts
#define SW1_OFF 0        // 2 x 4096 dwords (16KB each)
#define SW2_OFF 8192     // 2 x 4096 dwords
#define HB_OFF  16384    // 8 waves x 512 dwords
#define SC_OFF  20480    // 128 floats sscale
#define SH_OFF  20608    // 128 floats sshift
#define FFX_LDS_BYTES (20736 * 4)   // 82944 B

typedef short short8 __attribute__((ext_vector_type(8)));
typedef float floatx4 __attribute__((ext_vector_type(4)));

__device__ __forceinline__ float bfu2f(unsigned short u) {
    return __uint_as_float(((unsigned int)u) << 16);
}
__device__ __forceinline__ unsigned short f2bfu(float f) {
    union { __hip_bfloat16 h; unsigned short u; } cv;
    cv.h = __float2bfloat16(f);
    return cv.u;
}

// async global->LDS 16B: linear LDS dest (wave-uniform base + lane*16), per-lane global src
__device__ __forceinline__ void gld16(const unsigned int* g, unsigned int* l) {
    __builtin_amdgcn_global_load_lds(
        (const __attribute__((address_space(1))) unsigned int*)g,
        (__attribute__((address_space(3))) unsigned int*)l, 16, 0, 0);
}

// ---------------- init: bin cursors (fixed-capacity regions) + BN stat accumulators ----------------
__global__ void k_init(int* __restrict__ bincur, float* __restrict__ stats) {
    int i = blockIdx.x * 256 + threadIdx.x;
    if (i < NBIN) bincur[i] = i * CAP;
    if (i < 512) stats[i] = 0.f;   // [0..127]=sum1,[128..255]=sq1,[256..383]=sum2,[384..511]=sq2
}

// ---------------- CSR build pass 1: LDS multi-split into 128 FIXED-CAPACITY dst-bin regions ----
__global__ __launch_bounds__(256) void k_fill1(const int* __restrict__ src, const int* __restrict__ dst,
                                               int* __restrict__ bincur, unsigned int* __restrict__ recs) {
    __shared__ int lhist[NBIN], lbase[NBIN], gbase[NBIN];
    __shared__ unsigned int lrec[TILE];
    int tid = threadIdx.x;
    int tbase = blockIdx.x * TILE;
    if (tid < NBIN) lhist[tid] = 0;
    __syncthreads();
    unsigned int myrec[8];
    int mybin[8], myrank[8];
    #pragma unroll
    for (int j = 0; j < 8; ++j) {
        int e = tbase + j * 256 + tid;
        mybin[j] = -1;
        if (e < NE) {
            int d = __builtin_nontemporal_load(dst + e);
            int s = __builtin_nontemporal_load(src + e);
            int b = d / NPBIN;            // 0..127
            myrec[j] = (unsigned)s | ((unsigned)(d - b * NPBIN) << 17);
            mybin[j] = b;
            myrank[j] = atomicAdd(&lhist[b], 1);
        }
    }
    __syncthreads();
    if (tid == 0) {                        // exclusive scan of 128 bin counts
        int run = 0;
        #pragma unroll
        for (int b = 0; b < NBIN; ++b) { lbase[b] = run; run += lhist[b]; }
    }
    __syncthreads();
    if (tid < NBIN) gbase[tid] = atomicAdd(&bincur[tid], lhist[tid]);
    __syncthreads();
    #pragma unroll
    for (int j = 0; j < 8; ++j)
        if (mybin[j] >= 0) lrec[lbase[mybin[j]] + myrank[j]] = myrec[j];
    __syncthreads();
    int total = lbase[NBIN - 1] + lhist[NBIN - 1];
    for (int i = tid; i < total; i += 256) {
        int b = 0;                         // largest b with lbase[b] <= i (lbase monotone)
        #pragma unroll
        for (int st = NBIN / 2; st > 0; st >>= 1)
            if (b + st < NBIN && lbase[b + st] <= i) b += st;
        int p = gbase[b] + (i - lbase[b]);
        if (p < (b + 1) * CAP) recs[p] = lrec[i];   // capacity guard (12-sigma slack)
    }
}

// ---------------- per-bin LDS histogram -> cnt, one block per bin, NO global atomics --------
__global__ __launch_bounds__(256) void k_cnt(const unsigned int* __restrict__ recs,
                                             const int* __restrict__ bincur,
                                             int* __restrict__ cnt) {
    __shared__ int lhist[NPBIN];
    int b = blockIdx.x;
    int tid = threadIdx.x;
    for (int i = tid; i < NPBIN; i += 256) lhist[i] = 0;
    __syncthreads();
    int start = b * CAP;
    int end = bincur[b];
    if (end > start + CAP) end = start + CAP;
    if (end < start) end = start;
    for (int i = start + tid; i < end; i += 256) {
        unsigned int r = __builtin_nontemporal_load(recs + i);
        int dl = (int)(r >> 17);
        if (dl < NPBIN) atomicAdd(&lhist[dl], 1);
    }
    __syncthreads();
    for (int i = tid; i < NPBIN; i += 256) {
        int n = b * NPBIN + i;
        if (n < NN) cnt[n] = lhist[i];
    }
}

// ---------------- scan stage A: per-block (1024-wide) local exclusive scan + block sums + dinv ----
__global__ __launch_bounds__(1024) void k_scanA(const int* __restrict__ cnt, int* __restrict__ offs,
                                                int* __restrict__ bsum, float* __restrict__ dinv) {
    __shared__ int wsum[16];
    int t = threadIdx.x;          // 1024 threads = 16 waves
    int lane = t & 63, wid = t >> 6;
    int i = blockIdx.x * 1024 + t;
    int v = (i < NN) ? cnt[i] : 0;
    int incl = v;
    #pragma unroll
    for (int off = 1; off < 64; off <<= 1) {
        int y = __shfl_up(incl, off, 64);
        if (lane >= off) incl += y;
    }
    if (lane == 63) wsum[wid] = incl;
    __syncthreads();
    if (wid == 0) {
        int wv = (lane < 16) ? wsum[lane] : 0;
        int wincl = wv;
        #pragma unroll
        for (int off = 1; off < 16; off <<= 1) {
            int y = __shfl_up(wincl, off, 64);
            if (lane >= off) wincl += y;
        }
        if (lane < 16) wsum[lane] = wincl - wv;   // exclusive wave offsets
    }
    __syncthreads();
    int excl = wsum[wid] + incl - v;              // block-local exclusive
    if (i < NN) {
        offs[i] = excl;
        dinv[i] = rsqrtf((float)(v + 1));         // deg includes self-loop
    }
    if (t == 1023) bsum[blockIdx.x] = excl + v;   // block total
}

// ---------------- scan stage B: single block scans the 98 block sums ----------------
__global__ __launch_bounds__(128) void k_scanB(int* __restrict__ bsum, int* __restrict__ offs, int nblk) {
    int t = threadIdx.x;   // 128 >= nblk; two waves, use wave 0 only
    if (t < 64) {
        int v = (t < nblk) ? bsum[t] : 0;
        int v2 = (t + 64 < nblk) ? bsum[t + 64] : 0;
        int incl = v;
        #pragma unroll
        for (int off = 1; off < 64; off <<= 1) {
            int y = __shfl_up(incl, off, 64);
            if (t >= off) incl += y;
        }
        int tot0 = __shfl(incl, 63, 64);
        int incl2 = v2;
        #pragma unroll
        for (int off = 1; off < 64; off <<= 1) {
            int y = __shfl_up(incl2, off, 64);
            if (t >= off) incl2 += y;
        }
        if (t < nblk) bsum[t] = incl - v;                      // exclusive
        if (t + 64 < nblk) bsum[t + 64] = tot0 + incl2 - v2;
        if (t == 63) offs[NN] = tot0 + __shfl(incl2, 63, 64);  // grand total
    }
}

// ---------------- scan stage C: add block bases ----------------
__global__ void k_scanC(int* __restrict__ offs, const int* __restrict__ bsum) {
    int i = blockIdx.x * 256 + threadIdx.x;
    if (i < NN) offs[i] += bsum[i >> 10];
}

// ---------------- CSR build pass 2: per-bin scatter with LDS cursors, ZERO global atomics ----
__global__ __launch_bounds__(256) void k_fill2(const unsigned int* __restrict__ recs,
                                               const int* __restrict__ bincur,
                                               const int* __restrict__ offs,
                                               int* __restrict__ srcs) {
    __shared__ int loffs[NPBIN], lcur[NPBIN];
    int b = blockIdx.x;
    int tid = threadIdx.x;
    for (int i = tid; i < NPBIN; i += 256) {
        int n = b * NPBIN + i;
        loffs[i] = (n <= NN) ? offs[n] : NE;
        lcur[i] = 0;
    }
    __syncthreads();
    int start = b * CAP;
    int end = bincur[b];
    if (end > start + CAP) end = start + CAP;
    if (end < start) end = start;
    for (int i = start + tid; i < end; i += 256) {
        unsigned int r = __builtin_nontemporal_load(recs + i);
        int s = (int)(r & 0x1FFFFu);
        int dl = (int)(r >> 17);
        if (dl < NPBIN) {
            int p = loffs[dl] + atomicAdd(&lcur[dl], 1);
            if ((unsigned)p < NE) srcs[p] = s;
        }
    }
}

// ---------------- transpose W (fp32) -> bf16 wt[n][k] ----------------
__global__ void k_wt(const float* __restrict__ W, unsigned short* __restrict__ wt) {
    int i = blockIdx.x * 256 + threadIdx.x;
    if (i < DIM * DIM) {
        int k = i >> 7, n = i & 127;
        wt[n * DIM + k] = f2bfu(W[k * DIM + n]);
    }
}

// ---------------- prep FF weights: w1t[n=512][k=128], w2t[n=128][k=512] (bf16, transposed) -------
__global__ void k_prep(const float* __restrict__ w1, const float* __restrict__ w2,
                       unsigned short* __restrict__ w1t, unsigned short* __restrict__ w2t) {
    int i = blockIdx.x * 256 + threadIdx.x;
    if (i < HID * DIM) {
        int n1 = i >> 7, k1 = i & 127;           // w1t[n1*128+k1] = w1[k1*512+n1]
        w1t[i] = f2bfu(w1[k1 * HID + n1]);
        int n2 = i & 127, k2 = i >> 7;           // w2t[n2*512+k2] = w2[k2*DIM+n2]
        w2t[n2 * HID + k2] = f2bfu(w2[k2 * DIM + n2]);
    }
}

// ---------------- xw' = dinv .* (bf16(x) @ bf16(W)) via MFMA; dinv folded ----------------
__global__ __launch_bounds__(256) void k_gemm1(const float* __restrict__ x,
                                               const unsigned short* __restrict__ wt,
                                               const float* __restrict__ dinv,
                                               unsigned short* __restrict__ xw) {
    int wave = threadIdx.x >> 6;
    int lane = threadIdx.x & 63;
    int row0 = blockIdx.x * 64 + wave * 16;
    int arow = row0 + (lane & 15);
    if (arow >= NN) arow = NN - 1;        // clamp; stores are guarded
    int kbase = (lane >> 4) * 8;
    const float* xr = x + (size_t)arow * DIM;
    short8 afrag[4];
    #pragma unroll
    for (int kt = 0; kt < 4; ++kt) {
        float4 f0 = *(const float4*)(xr + kt * 32 + kbase);
        float4 f1 = *(const float4*)(xr + kt * 32 + kbase + 4);
        short8 a;
        a[0] = (short)f2bfu(f0.x); a[1] = (short)f2bfu(f0.y);
        a[2] = (short)f2bfu(f0.z); a[3] = (short)f2bfu(f0.w);
        a[4] = (short)f2bfu(f1.x); a[5] = (short)f2bfu(f1.y);
        a[6] = (short)f2bfu(f1.z); a[7] = (short)f2bfu(f1.w);
        afrag[kt] = a;                     // A[m=lane&15][k=quad*8+j]
    }
    int crow = row0 + (lane >> 4) * 4;
    float dv[4];
    #pragma unroll
    for (int i = 0; i < 4; ++i) {
        int r = crow + i;
        dv[i] = dinv[r < NN ? r : NN - 1];
    }
    #pragma unroll
    for (int ct = 0; ct < 8; ++ct) {
        int ncol = ct * 16 + (lane & 15);
        const short* wr = (const short*)wt + (size_t)ncol * DIM;
        floatx4 acc = {0.f, 0.f, 0.f, 0.f};
        #pragma unroll
        for (int kt = 0; kt < 4; ++kt) {
            short8 bfrag = *(const short8*)(wr + kt * 32 + kbase); // B[k=quad*8+j][n=lane&15]
            acc = __builtin_amdgcn_mfma_f32_16x16x32_bf16(afrag[kt], bfrag, acc, 0, 0, 0);
        }
        #pragma unroll
        for (int i = 0; i < 4; ++i) {
            int r = crow + i;                  // C: row=(lane>>4)*4+reg, col=lane&15
            if (r < NN) xw[(size_t)r * DIM + ct * 16 + (lane & 15)] = f2bfu(acc[i] * dv[i]);
        }
    }
}

// ---------------- aggregate v4: register-blocked indices + QUAD edge pairing ----------------
__global__ __launch_bounds__(256) void k_aggregate(const unsigned int* __restrict__ xw2,
                                                   const int* __restrict__ offs,
                                                   const int* __restrict__ srcs,
                                                   const float* __restrict__ dinv,
                                                   const float* __restrict__ x,
                                                   const float* __restrict__ bias,
                                                   unsigned int* __restrict__ u) {
    int node = blockIdx.x * 4 + (threadIdx.x >> 6);
    if (node >= NN) return;
    int lane = threadIdx.x & 63;
    int qt = lane >> 4;              // edge slot within quad (0..3)
    int ql = lane & 15;              // handles cols 8*ql .. 8*ql+7
    int beg = offs[node], end = offs[node + 1];
    beg = max(0, min(beg, NE));
    end = max(beg, min(end, NE));
    int ne = end - beg;
    float a[8];
    #pragma unroll
    for (int j = 0; j < 8; ++j) a[j] = 0.f;
    const uint4* xw16 = (const uint4*)xw2;       // row = 16 uint4 (256B)
    for (int base = 0; base < ne; base += 64) {
        int rem = ne - base;
        if (rem > 64) rem = 64;
        int sidx = (lane < rem) ? srcs[beg + base + lane] : 0;
        #pragma unroll 4
        for (int i = 0; i < rem; i += 4) {
            int want = i + qt;
            int s = __builtin_amdgcn_ds_bpermute(want << 2, sidx);
            if (want < rem) {
                if ((unsigned)s >= NN) s = 0;
                uint4 pk = xw16[(size_t)s * 16 + ql];
                a[0] += __uint_as_float(pk.x << 16);
                a[1] += __uint_as_float(pk.x & 0xffff0000u);
                a[2] += __uint_as_float(pk.y << 16);
                a[3] += __uint_as_float(pk.y & 0xffff0000u);
                a[4] += __uint_as_float(pk.z << 16);
                a[5] += __uint_as_float(pk.z & 0xffff0000u);
                a[6] += __uint_as_float(pk.w << 16);
                a[7] += __uint_as_float(pk.w & 0xffff0000u);
            }
        }
    }
    // combine the 4 quad partial sums (all lanes end with the full sum)
    #pragma unroll
    for (int j = 0; j < 8; ++j) {
        a[j] += __shfl_xor(a[j], 16, 64);
        a[j] += __shfl_xor(a[j], 32, 64);
    }
    if (qt == 0) {                   // lanes 0..15 write the 256B row
        uint4 ps = xw16[(size_t)node * 16 + ql];
        float di = dinv[node];
        const float* xr = x + (size_t)node * DIM + ql * 8;
        float4 xv0 = *(const float4*)xr;
        float4 xv1 = *(const float4*)(xr + 4);
        float4 bv0 = *(const float4*)(bias + ql * 8);
        float4 bv1 = *(const float4*)(bias + ql * 8 + 4);
        float o0 = xv0.x + bv0.x + di * (a[0] + __uint_as_float(ps.x << 16));
        float o1 = xv0.y + bv0.y + di * (a[1] + __uint_as_float(ps.x & 0xffff0000u));
        float o2 = xv0.z + bv0.z + di * (a[2] + __uint_as_float(ps.y << 16));
        float o3 = xv0.w + bv0.w + di * (a[3] + __uint_as_float(ps.y & 0xffff0000u));
        float o4 = xv1.x + bv1.x + di * (a[4] + __uint_as_float(ps.z << 16));
        float o5 = xv1.y + bv1.y + di * (a[5] + __uint_as_float(ps.z & 0xffff0000u));
        float o6 = xv1.z + bv1.z + di * (a[6] + __uint_as_float(ps.w << 16));
        float o7 = xv1.w + bv1.w + di * (a[7] + __uint_as_float(ps.w & 0xffff0000u));
        uint4 pk;
        pk.x = ((unsigned int)f2bfu(o1) << 16) | (unsigned int)f2bfu(o0);
        pk.y = ((unsigned int)f2bfu(o3) << 16) | (unsigned int)f2bfu(o2);
        pk.z = ((unsigned int)f2bfu(o5) << 16) | (unsigned int)f2bfu(o4);
        pk.w = ((unsigned int)f2bfu(o7) << 16) | (unsigned int)f2bfu(o6);
        ((uint4*)u)[(size_t)node * 16 + ql] = pk;
    }
}

// ---------------- BN1 stats: per-column sum & sumsq of u (bf16) ----------------
__global__ void k_stats(const unsigned int* __restrict__ u2, float* __restrict__ stats) {
    int t = threadIdx.x;            // 256
    int c = t & 63, g = t >> 6;     // uint index c -> bf16 cols 2c, 2c+1
    float s0 = 0.f, q0 = 0.f, s1 = 0.f, q1 = 0.f;
    for (int r = blockIdx.x * 4 + g; r < NN; r += gridDim.x * 4) {
        unsigned int pv = u2[(size_t)r * 64 + c];
        float x0 = __uint_as_float(pv << 16);
        float x1 = __uint_as_float(pv & 0xffff0000u);
        s0 += x0; q0 += x0 * x0; s1 += x1; q1 += x1 * x1;
    }
    __shared__ float A[256], B[256], C[256], D2[256];
    A[t] = s0; B[t] = q0; C[t] = s1; D2[t] = q1;
    __syncthreads();
    if (t < 64) {
        float rs0 = A[t] + A[t + 64] + A[t + 128] + A[t + 192];
        float rq0 = B[t] + B[t + 64] + B[t + 128] + B[t + 192];
        float rs1 = C[t] + C[t + 64] + C[t + 128] + C[t + 192];
        float rq1 = D2[t] + D2[t + 64] + D2[t + 128] + D2[t + 192];
        atomicAdd(&stats[2 * c],           rs0);
        atomicAdd(&stats[2 * c + 1],       rs1);
        atomicAdd(&stats[DIM + 2 * c],     rq0);
        atomicAdd(&stats[DIM + 2 * c + 1], rq1);
    }
}

// ---------------- BN2 stats: per-column sum & sumsq of v (fp32) ----------------
__global__ void k_stats2(const float2* __restrict__ v2, float* __restrict__ stats) {
    int t = threadIdx.x;            // 256
    int c = t & 63, g = t >> 6;     // float2 index c -> cols 2c, 2c+1
    float s0 = 0.f, q0 = 0.f, s1 = 0.f, q1 = 0.f;
    for (int r = blockIdx.x * 4 + g; r < NN; r += gridDim.x * 4) {
        float2 pv = v2[(size_t)r * 64 + c];
        s0 += pv.x; q0 += pv.x * pv.x; s1 += pv.y; q1 += pv.y * pv.y;
    }
    __shared__ float A[256], B[256], C[256], D2[256];
    A[t] = s0; B[t] = q0; C[t] = s1; D2[t] = q1;
    __syncthreads();
    if (t < 64) {
        float rs0 = A[t] + A[t + 64] + A[t + 128] + A[t + 192];
        float rq0 = B[t] + B[t + 64] + B[t + 128] + B[t + 192];
        float rs1 = C[t] + C[t + 64] + C[t + 128] + C[t + 192];
        float rq1 = D2[t] + D2[t + 64] + D2[t + 128] + D2[t + 192];
        atomicAdd(&stats[2 * c],           rs0);
        atomicAdd(&stats[2 * c + 1],       rs1);
        atomicAdd(&stats[DIM + 2 * c],     rq0);
        atomicAdd(&stats[DIM + 2 * c + 1], rq1);
    }
}

// ---------------- fused FF v6: double-buffered global_load_lds weight staging ----------------
// r13: all pipes idle (Mfma 8.6, VALU 11, HBM 8, occ 16) -> serial stage->barrier->compute.
// Fix: async global_load_lds (no VGPR round-trip) into 2x LDS buffers; loads for chunk c+1
// are issued AFTER the barrier and stay in flight under chunk c's MFMAs; the next barrier
// drains them. LDS dest is LINEAR (gload_lds constraint); the XOR swizzle is applied to the
// GLOBAL source column (s ^ (row&7)) so read-side indexing is unchanged (m173 pattern).
// 1 barrier/chunk (was 2). Dynamic LDS 81KB (2x16KB w1 + 2x16KB w2 + 16KB hbufs + 1KB BN).
__global__ __launch_bounds__(512) void k_ffx(const unsigned int* __restrict__ u2,
                                             const float* __restrict__ stats1,
                                             const float* __restrict__ gamma,
                                             const float* __restrict__ beta,
                                             const unsigned short* __restrict__ w1t,
                                             const float* __restrict__ b1,
                                             const unsigned short* __restrict__ w2t,
                                             const float* __restrict__ b2,
                                             float* __restrict__ v) {
    extern __shared__ unsigned int smem[];
    float* sscale = (float*)(smem + SC_OFF);
    float* sshift = (float*)(smem + SH_OFF);
    int tid = threadIdx.x;
    if (tid < DIM) {
        float mu  = stats1[tid] * (1.0f / NN);
        float var = stats1[DIM + tid] * (1.0f / NN) - mu * mu;
        float sc = rsqrtf(var + BN_EPS) * gamma[tid];
        sscale[tid] = sc;
        sshift[tid] = beta[tid] - mu * sc;
    }
    __syncthreads();
    int wave = tid >> 6, lane = tid & 63;        // wave 0..7
    int m = lane & 15, q = lane >> 4;
    int nb = blockIdx.x * 256 + wave * 32;       // this wave's 32 nodes
    unsigned int* hb = smem + HB_OFF + wave * 512;
    const int xsw = (m & 7) * 4;                 // per-lane XOR swizzle (dwords)

    const uint4* w1g = (const uint4*)w1t;   // row n: 16 uint4
    const uint4* w2g = (const uint4*)w2t;   // row n: 64 uint4

    // async stage of chunk c into buffer buf: linear LDS dest, source column pre-swizzled
    auto stage = [&](int c, int buf) {
        #pragma unroll
        for (int it = 0; it < 2; ++it) {
            int i = tid + it * 512;
            int j = i >> 4, s4 = i & 15;
            gld16((const unsigned int*)&w1g[(size_t)(c * 64 + j) * 16 + (s4 ^ (j & 7))],
                  smem + SW1_OFF + buf * 4096 + i * 4);
            int n = i >> 3, s8 = i & 7;
            gld16((const unsigned int*)&w2g[(size_t)n * 64 + c * 8 + (s8 ^ (n & 7))],
                  smem + SW2_OFF + buf * 4096 + i * 4);
        }
    };
    stage(0, 0);    // in flight during yfrag build; drained by the loop's first barrier

    // build yfrags: y1 = BN1(u) for this wave's 2 strips, direct from global
    short8 yfrag[2][4];
    #pragma unroll
    for (int s = 0; s < 2; ++s) {
        int ng = nb + s * 16 + m;
        if (ng >= NN) ng = NN - 1;
        const uint4* up = (const uint4*)(u2 + (size_t)ng * 64);
        #pragma unroll
        for (int kt = 0; kt < 4; ++kt) {
            uint4 pv = up[kt * 4 + q];
            int c0 = kt * 32 + q * 8;
            float4 sa = *(const float4*)&sscale[c0], sb = *(const float4*)&sscale[c0 + 4];
            float4 ha = *(const float4*)&sshift[c0], hbv = *(const float4*)&sshift[c0 + 4];
            float f0 = __uint_as_float(pv.x << 16)         * sa.x + ha.x;
            float f1 = __uint_as_float(pv.x & 0xffff0000u) * sa.y + ha.y;
            float f2 = __uint_as_float(pv.y << 16)         * sa.z + ha.z;
            float f3 = __uint_as_float(pv.y & 0xffff0000u) * sa.w + ha.w;
            float f4 = __uint_as_float(pv.z << 16)         * sb.x + hbv.x;
            float f5 = __uint_as_float(pv.z & 0xffff0000u) * sb.y + hbv.y;
            float f6 = __uint_as_float(pv.w << 16)         * sb.z + hbv.z;
            float f7 = __uint_as_float(pv.w & 0xffff0000u) * sb.w + hbv.w;
            union { unsigned int u[4]; short8 sv; } yf;
            yf.u[0] = ((unsigned int)f2bfu(f1) << 16) | f2bfu(f0);
            yf.u[1] = ((unsigned int)f2bfu(f3) << 16) | f2bfu(f2);
            yf.u[2] = ((unsigned int)f2bfu(f5) << 16) | f2bfu(f4);
            yf.u[3] = ((unsigned int)f2bfu(f7) << 16) | f2bfu(f6);
            yfrag[s][kt] = yf.sv;
        }
    }

    floatx4 acc2[2][8];
    #pragma unroll
    for (int s = 0; s < 2; ++s)
        #pragma unroll
        for (int t = 0; t < 8; ++t) acc2[s][t] = (floatx4){0.f, 0.f, 0.f, 0.f};

    for (int c = 0; c < 8; ++c) {
        int cur = c & 1;
        __syncthreads();                     // drains stage(c) loads (vmcnt0) + joins all waves
        if (c < 7) stage(c + 1, cur ^ 1);    // async: in flight under this chunk's MFMAs
        const unsigned int* sw1 = smem + SW1_OFF + cur * 4096;
        const unsigned int* sw2 = smem + SW2_OFF + cur * 4096;
        #pragma unroll
        for (int s = 0; s < 2; ++s) {
            // gemm1T: h^T(64 hid x 16 node) for this strip
            floatx4 acc1[4];
            #pragma unroll
            for (int t = 0; t < 4; ++t) acc1[t] = (floatx4){0.f, 0.f, 0.f, 0.f};
            #pragma unroll
            for (int kt = 0; kt < 4; ++kt) {
                #pragma unroll
                for (int t = 0; t < 4; ++t) {
                    short8 wf = *(const short8*)&sw1[(t * 16 + m) * 64 + ((kt * 16 + q * 4) ^ xsw)];
                    acc1[t] = __builtin_amdgcn_mfma_f32_16x16x32_bf16(wf, yfrag[s][kt], acc1[t], 0, 0, 0);
                }
            }
            // relu + bias -> hbuf (lane holds h[node=m][hid=c*64 + t*16 + q*4 + i])
            #pragma unroll
            for (int t = 0; t < 4; ++t) {
                float4 bb = *(const float4*)&b1[c * 64 + t * 16 + q * 4];
                float h0 = fmaxf(acc1[t][0] + bb.x, 0.f);
                float h1 = fmaxf(acc1[t][1] + bb.y, 0.f);
                float h2 = fmaxf(acc1[t][2] + bb.z, 0.f);
                float h3 = fmaxf(acc1[t][3] + bb.w, 0.f);
                uint2 hp;
                hp.x = ((unsigned int)f2bfu(h1) << 16) | f2bfu(h0);
                hp.y = ((unsigned int)f2bfu(h3) << 16) | f2bfu(h2);
                *(uint2*)&hb[m * 32 + ((t * 8 + q * 2) ^ xsw)] = hp;
            }
            // gemm2: acc2 += h(16 node x 64 k) x w2c(64 k x 128 out)
            #pragma unroll
            for (int kt = 0; kt < 2; ++kt) {
                short8 hf = *(const short8*)&hb[m * 32 + ((kt * 16 + q * 4) ^ xsw)];
                #pragma unroll
                for (int t = 0; t < 8; ++t) {
                    short8 wf2 = *(const short8*)&sw2[(t * 16 + m) * 32 + ((kt * 16 + q * 4) ^ xsw)];
                    acc2[s][t] = __builtin_amdgcn_mfma_f32_16x16x32_bf16(hf, wf2, acc2[s][t], 0, 0, 0);
                }
            }
        }
    }
    // epilogue: C acc2[s][t]: node = q*4+i, outcol = t*16+m; v = y1 + ff + b2
    #pragma unroll
    for (int s = 0; s < 2; ++s) {
        #pragma unroll
        for (int t = 0; t < 8; ++t) {
            int col = t * 16 + m;
            float b2v = b2[col];
            float scl = sscale[col], shf = sshift[col];
            #pragma unroll
            for (int i = 0; i < 4; ++i) {
                int ng = nb + s * 16 + q * 4 + i;
                if (ng < NN) {
                    unsigned int pv = u2[(size_t)ng * 64 + (col >> 1)];
                    float uval = (col & 1) ? __uint_as_float(pv & 0xffff0000u)
                                           : __uint_as_float(pv << 16);
                    v[(size_t)ng * DIM + col] = acc2[s][t][i] + b2v + (uval * scl + shf);
                }
            }
        }
    }
}

// ---------------- final BN2 in place on v (fp32, in d_out) ----------------
__global__ void k_final(float* buf, const float* __restrict__ stats2,
                        const float* __restrict__ gamma,
                        const float* __restrict__ beta) {
    __shared__ float ssc[DIM], ssh[DIM];
    int t = threadIdx.x;
    if (t < DIM) {
        float mu  = stats2[t] * (1.0f / NN);
        float var = stats2[DIM + t] * (1.0f / NN) - mu * mu;
        float rsg = rsqrtf(var + BN_EPS) * gamma[t];
        ssc[t] = rsg;
        ssh[t] = beta[t] - mu * rsg;
    }
    __syncthreads();
    const int total = NN * DIM / 4;   // float4s
    float4* b4 = (float4*)buf;
    for (int i = blockIdx.x * blockDim.x + t; i < total; i += gridDim.x * blockDim.x) {
        float4 val = b4[i];
        int c = (i * 4) & (DIM - 1);
        val.x = val.x * ssc[c]     + ssh[c];
        val.y = val.y * ssc[c + 1] + ssh[c + 1];
        val.z = val.z * ssc[c + 2] + ssh[c + 2];
        val.w = val.w * ssc[c + 3] + ssh[c + 3];
        b4[i] = val;
    }
}

extern "C" void kernel_launch(void* const* d_in, const int* in_sizes, int n_in,
                              void* d_out, int out_size, void* d_ws, size_t ws_size,
                              hipStream_t stream) {
    const float* x     = (const float*)d_in[0];
    const int*   ei    = (const int*)d_in[1];
    const float* W     = (const float*)d_in[2];
    const float* b     = (const float*)d_in[3];
    const float* gamma = (const float*)d_in[4];
    const float* beta  = (const float*)d_in[5];
    const float* w1    = (const float*)d_in[6];
    const float* b1    = (const float*)d_in[7];
    const float* w2    = (const float*)d_in[8];
    const float* b2    = (const float*)d_in[9];

    // workspace bump allocator (~26.5 MB), 256B-aligned regions
    char* p = (char*)d_ws;
    auto alloc = [&](size_t bytes) { char* r = p; p += (bytes + 255) & ~(size_t)255; return r; };
    unsigned int*   u     = (unsigned int*)alloc((size_t)NN * DIM * 2);   // u = x + h, bf16 packed
    int*            cnt   = (int*)alloc((size_t)NN * 4);
    int*            offs  = (int*)alloc((size_t)(NN + 1) * 4);
    float*          dinv  = (float*)alloc((size_t)NN * 4);
    int*            bsum  = (int*)alloc(128 * 4);
    int*            bincur = (int*)alloc((size_t)NBIN * 4);
    unsigned short* wt    = (unsigned short*)alloc((size_t)DIM * DIM * 2);
    unsigned short* w1t   = (unsigned short*)alloc((size_t)HID * DIM * 2);
    unsigned short* w2t   = (unsigned short*)alloc((size_t)HID * DIM * 2);
    float*          stats = (float*)alloc(512 * 4);

    // d_out (51.2 MB fp32) doubles as scratch during the graph phase:
    //   [0, 13.82MB)     recs (uint, NBIN*CAP) — fixed-capacity bin records; dead after
    //                    k_fill2; region then overwritten by k_gemm1's xw [0, 25.6MB)
    //   [25.6, 38.4MB)   srcs (int, NE)
    // All dead before k_ffx writes v over [0, 51.2MB).
    unsigned short* xw   = (unsigned short*)d_out;
    unsigned int*   recs = (unsigned int*)d_out;
    int*            srcs = (int*)((char*)d_out + (size_t)NN * DIM * 2);
    float*          v    = (float*)d_out;

    const int* esrc = ei;
    const int* edst = ei + NE;
    const int nblk = (NN + 1023) / 1024;   // 98
    const int n1blk = (NE + TILE - 1) / TILE;   // 1563

    k_init<<<2, 256, 0, stream>>>(bincur, stats);
    k_fill1<<<n1blk, 256, 0, stream>>>(esrc, edst, bincur, recs);
    k_cnt<<<NBIN, 256, 0, stream>>>(recs, bincur, cnt);
    k_scanA<<<nblk, 1024, 0, stream>>>(cnt, offs, bsum, dinv);
    k_scanB<<<1, 128, 0, stream>>>(bsum, offs, nblk);
    k_scanC<<<(NN + 255) / 256, 256, 0, stream>>>(offs, bsum);
    k_fill2<<<NBIN, 256, 0, stream>>>(recs, bincur, offs, srcs);
    k_wt<<<(DIM * DIM + 255) / 256, 256, 0, stream>>>(W, wt);
    k_prep<<<(HID * DIM + 255) / 256, 256, 0, stream>>>(w1, w2, w1t, w2t);
    k_gemm1<<<(NN + 63) / 64, 256, 0, stream>>>(x, wt, dinv, xw);
    k_aggregate<<<(NN + 3) / 4, 256, 0, stream>>>((const unsigned int*)xw, offs, srcs, dinv, x, b, u);
    k_stats<<<512, 256, 0, stream>>>(u, stats);
    k_ffx<<<(NN + 255) / 256, 512, FFX_LDS_BYTES, stream>>>(u, stats, gamma, beta, w1t, b1, w2t, b2, v);
    k_stats2<<<512, 256, 0, stream>>>((const float2*)v, stats + 256);
    k_final<<<2048, 256, 0, stream>>>((float*)d_out, stats + 256, gamma, beta);
}